// Round 1
// baseline (970.389 us; speedup 1.0000x reference)
//
#include <hip/hip_runtime.h>
#include <math.h>

#define B_SZ    2
#define L_SEQ   1024
#define DMODEL  1024
#define DINNER  2048
#define DSTATE  16
#define EPSV    1e-6f

// ---------------------------------------------------------------------------
// fp32 tiled GEMM: C = epilogue(A @ W + bias), A: MxK, W: KxN (both row-major)
// 64x64 tile, BK=16, 256 threads, 4x4 micro-tile per thread.
// MODE 0: +bias; MODE 1: softplus(+bias); MODE 2: +bias + resid
// Requires M%64==0, N%64==0, K%16==0 (true for all three GEMMs here).
// ---------------------------------------------------------------------------
template <int MODE>
__global__ __launch_bounds__(256) void gemm_f32(
    const float* __restrict__ A, const float* __restrict__ W,
    const float* __restrict__ bias, const float* __restrict__ resid,
    float* __restrict__ C, int M, int N, int K)
{
    __shared__ float As[16][64];   // [k][m]
    __shared__ float Bs[16][64];   // [k][n]
    const int tid = threadIdx.x;
    const int m0 = blockIdx.y * 64;
    const int n0 = blockIdx.x * 64;
    const int tx = tid & 15;       // col group
    const int ty = tid >> 4;       // row group

    const int arow = tid >> 2;           // 0..63
    const int ak4  = (tid & 3) << 2;     // 0,4,8,12
    const int brow = tid >> 4;           // 0..15
    const int bn4  = (tid & 15) << 2;    // 0..60

    float acc[4][4] = {};

    for (int kt = 0; kt < K; kt += 16) {
        float4 av = *(const float4*)&A[(size_t)(m0 + arow) * K + kt + ak4];
        float4 bv = *(const float4*)&W[(size_t)(kt + brow) * N + n0 + bn4];
        __syncthreads();  // previous iteration's LDS reads complete
        As[ak4 + 0][arow] = av.x;
        As[ak4 + 1][arow] = av.y;
        As[ak4 + 2][arow] = av.z;
        As[ak4 + 3][arow] = av.w;
        *(float4*)&Bs[brow][bn4] = bv;
        __syncthreads();
#pragma unroll
        for (int k = 0; k < 16; ++k) {
            float4 a4 = *(const float4*)&As[k][ty * 4];
            float4 b4 = *(const float4*)&Bs[k][tx * 4];
            float a[4] = {a4.x, a4.y, a4.z, a4.w};
            float b[4] = {b4.x, b4.y, b4.z, b4.w};
#pragma unroll
            for (int i = 0; i < 4; ++i)
#pragma unroll
                for (int j = 0; j < 4; ++j)
                    acc[i][j] = fmaf(a[i], b[j], acc[i][j]);
        }
    }

#pragma unroll
    for (int i = 0; i < 4; ++i) {
        const int row = m0 + ty * 4 + i;
#pragma unroll
        for (int j = 0; j < 4; ++j) {
            const int col = n0 + tx * 4 + j;
            float v = acc[i][j] + bias[col];
            if (MODE == 1) {
                v = (v > 20.f) ? v : log1pf(__expf(v));   // softplus
            } else if (MODE == 2) {
                v += resid[(size_t)row * N + col];
            }
            C[(size_t)row * N + col] = v;
        }
    }
}

// ---------------------------------------------------------------------------
// Depthwise causal conv1d (k=4) + SiLU. x_in = xz[..., :DINNER].
// One thread per (b,l, 4 channels).
// ---------------------------------------------------------------------------
__global__ __launch_bounds__(256) void conv_silu(
    const float* __restrict__ xz, const float* __restrict__ conv_w,
    const float* __restrict__ conv_b, float* __restrict__ x_conv)
{
    const int idx = blockIdx.x * 256 + threadIdx.x;   // [0, B*L*DINNER/4)
    const int c4  = (idx & (DINNER / 4 - 1)) << 2;    // channel*4
    const int row = idx >> 9;                         // b*L + l
    const int l   = row & (L_SEQ - 1);

    // conv_w[c][h] = conv_w[c*4+h]; per channel the 4 taps are contiguous.
    float4 w0 = *(const float4*)&conv_w[(c4 + 0) * 4];
    float4 w1 = *(const float4*)&conv_w[(c4 + 1) * 4];
    float4 w2 = *(const float4*)&conv_w[(c4 + 2) * 4];
    float4 w3 = *(const float4*)&conv_w[(c4 + 3) * 4];
    const float wt[4][4] = {{w0.x, w0.y, w0.z, w0.w},
                            {w1.x, w1.y, w1.z, w1.w},
                            {w2.x, w2.y, w2.z, w2.w},
                            {w3.x, w3.y, w3.z, w3.w}};
    float4 cb = *(const float4*)&conv_b[c4];
    float acc[4] = {cb.x, cb.y, cb.z, cb.w};

#pragma unroll
    for (int h = 0; h < 4; ++h) {
        const int lsrc = l - 3 + h;
        if (lsrc >= 0) {
            float4 xv = *(const float4*)&xz[(size_t)(row - 3 + h) * (2 * DINNER) + c4];
            acc[0] += xv.x * wt[0][h];
            acc[1] += xv.y * wt[1][h];
            acc[2] += xv.z * wt[2][h];
            acc[3] += xv.w * wt[3][h];
        }
    }
    float4 o;
    o.x = acc[0] / (1.f + __expf(-acc[0]));
    o.y = acc[1] / (1.f + __expf(-acc[1]));
    o.z = acc[2] / (1.f + __expf(-acc[2]));
    o.w = acc[3] / (1.f + __expf(-acc[3]));
    *(float4*)&x_conv[(size_t)row * DINNER + c4] = o;
}

// ---------------------------------------------------------------------------
// x_proj: BC[row][0:32] = x_conv[row] @ W_xp + b_xp  (N=32, K=2048)
// One block per row; 8 k-groups x 32 outputs.
// ---------------------------------------------------------------------------
__global__ __launch_bounds__(256) void xproj_kernel(
    const float* __restrict__ x_conv, const float* __restrict__ W_xp,
    const float* __restrict__ b_xp, float* __restrict__ BC)
{
    __shared__ float red[8][32];
    const int row = blockIdx.x;
    const int n = threadIdx.x & 31;
    const int g = threadIdx.x >> 5;
    const float* xr = x_conv + (size_t)row * DINNER;
    float p = 0.f;
    const int k0 = g * (DINNER / 8);
#pragma unroll 8
    for (int k = k0; k < k0 + DINNER / 8; ++k)
        p = fmaf(xr[k], W_xp[k * 32 + n], p);
    red[g][n] = p;
    __syncthreads();
    if (threadIdx.x < 32) {
        float ssum = b_xp[n];
#pragma unroll
        for (int gg = 0; gg < 8; ++gg) ssum += red[gg][n];
        BC[(size_t)row * 32 + n] = ssum;
    }
}

// ---------------------------------------------------------------------------
// Selective scan, fused with D_skip and z-gate.
// Block: 256 threads = 16 channel-groups x 16 states. Grid: B * DINNER/16.
// 64-step chunks staged in LDS.
// ---------------------------------------------------------------------------
__global__ __launch_bounds__(256) void scan_kernel(
    const float* __restrict__ delta, const float* __restrict__ x_conv,
    const float* __restrict__ BC, const float* __restrict__ A_log,
    const float* __restrict__ D_skip, const float* __restrict__ xz,
    float* __restrict__ y)
{
    __shared__ float sD[64][16];
    __shared__ float sX[64][16];
    __shared__ float sBC[64][32];
    __shared__ float sY[64][16];

    const int tid = threadIdx.x;
    const int b  = blockIdx.x >> 7;
    const int d0 = (blockIdx.x & 127) << 4;
    const int g = tid >> 4;    // channel within block
    const int s = tid & 15;    // state index
    const int d = d0 + g;

    const float Av  = -__expf(A_log[d * DSTATE + s]);
    const float Dsk = D_skip[d];
    float h = 0.f;

    const int jj = tid >> 2;        // staging row 0..63
    const int q4 = (tid & 3) << 2;  // 0,4,8,12

    for (int l0 = 0; l0 < L_SEQ; l0 += 64) {
        const size_t rbase = (size_t)(b * L_SEQ + l0 + jj);
        float4 dv  = *(const float4*)&delta[rbase * DINNER + d0 + q4];
        float4 xv  = *(const float4*)&x_conv[rbase * DINNER + d0 + q4];
        float4 bc0 = *(const float4*)&BC[rbase * 32 + q4];
        float4 bc1 = *(const float4*)&BC[rbase * 32 + 16 + q4];
        __syncthreads();  // prior chunk fully consumed
        *(float4*)&sD[jj][q4] = dv;
        *(float4*)&sX[jj][q4] = xv;
        *(float4*)&sBC[jj][q4] = bc0;
        *(float4*)&sBC[jj][16 + q4] = bc1;
        __syncthreads();

#pragma unroll 4
        for (int j = 0; j < 64; ++j) {
            const float dl = sD[j][g];
            const float xc = sX[j][g];
            const float bv = sBC[j][s];
            const float cv = sBC[j][16 + s];
            h = __expf(dl * Av) * h + dl * xc * bv;
            float p = h * cv;
            p += __shfl_xor(p, 1);
            p += __shfl_xor(p, 2);
            p += __shfl_xor(p, 4);
            p += __shfl_xor(p, 8);
            if (s == 0) sY[j][g] = p + Dsk * xc;
        }
        __syncthreads();

        // gated write: y = sY * silu(z)
        {
            float4 zv = *(const float4*)&xz[rbase * (2 * DINNER) + DINNER + d0 + q4];
            float4 yv = *(const float4*)&sY[jj][q4];
            float4 o;
            o.x = yv.x * (zv.x / (1.f + __expf(-zv.x)));
            o.y = yv.y * (zv.y / (1.f + __expf(-zv.y)));
            o.z = yv.z * (zv.z / (1.f + __expf(-zv.z)));
            o.w = yv.w * (zv.w / (1.f + __expf(-zv.w)));
            *(float4*)&y[rbase * DINNER + d0 + q4] = o;
        }
    }
}

// ---------------------------------------------------------------------------
// Row LayerNorm: unbiased variance (N-1), eps added to std.
// One block (256 threads, 4 elems each) per row of 1024.
// ---------------------------------------------------------------------------
__global__ __launch_bounds__(256) void layernorm_kernel(
    const float* __restrict__ t, const float* __restrict__ alpha,
    const float* __restrict__ beta, float* __restrict__ out)
{
    __shared__ float sred[4];
    __shared__ float sred2[4];
    const int row = blockIdx.x;
    const int tid = threadIdx.x;
    const float* r = t + (size_t)row * DMODEL;

    float4 v = *(const float4*)&r[tid * 4];
    float lsum = v.x + v.y + v.z + v.w;
#pragma unroll
    for (int m = 1; m < 64; m <<= 1) lsum += __shfl_xor(lsum, m);
    if ((tid & 63) == 0) sred[tid >> 6] = lsum;
    __syncthreads();
    const float mean = (sred[0] + sred[1] + sred[2] + sred[3]) * (1.f / DMODEL);

    const float dx = v.x - mean, dy = v.y - mean, dz = v.z - mean, dw = v.w - mean;
    float ls2 = dx * dx + dy * dy + dz * dz + dw * dw;
#pragma unroll
    for (int m = 1; m < 64; m <<= 1) ls2 += __shfl_xor(ls2, m);
    if ((tid & 63) == 0) sred2[tid >> 6] = ls2;
    __syncthreads();
    const float var = (sred2[0] + sred2[1] + sred2[2] + sred2[3]) * (1.f / (DMODEL - 1));
    const float inv = 1.f / (sqrtf(var) + EPSV);

    float4 a4 = *(const float4*)&alpha[tid * 4];
    float4 b4 = *(const float4*)&beta[tid * 4];
    float4 o;
    o.x = a4.x * dx * inv + b4.x;
    o.y = a4.y * dy * inv + b4.y;
    o.z = a4.z * dz * inv + b4.z;
    o.w = a4.w * dw * inv + b4.w;
    *(float4*)&out[(size_t)row * DMODEL + tid * 4] = o;
}

// ---------------------------------------------------------------------------
extern "C" void kernel_launch(void* const* d_in, const int* in_sizes, int n_in,
                              void* d_out, int out_size, void* d_ws, size_t ws_size,
                              hipStream_t stream)
{
    const float* x      = (const float*)d_in[0];
    const float* W_in   = (const float*)d_in[1];
    const float* b_in   = (const float*)d_in[2];
    const float* conv_w = (const float*)d_in[3];
    const float* conv_b = (const float*)d_in[4];
    const float* W_xp   = (const float*)d_in[5];
    const float* b_xp   = (const float*)d_in[6];
    const float* W_dt   = (const float*)d_in[7];
    const float* b_dt   = (const float*)d_in[8];
    const float* A_log  = (const float*)d_in[9];
    const float* D_skip = (const float*)d_in[10];
    const float* W_out  = (const float*)d_in[11];
    const float* b_out  = (const float*)d_in[12];
    const float* alpha  = (const float*)d_in[13];
    const float* beta   = (const float*)d_in[14];
    float* out = (float*)d_out;

    const size_t M = (size_t)B_SZ * L_SEQ;  // 2048 rows
    float* ws      = (float*)d_ws;
    float* xz      = ws;                       // M * 4096
    float* x_conv  = xz + M * 4096;            // M * 2048
    float* BC      = x_conv + M * 2048;        // M * 32
    float* delta   = BC + M * 32;              // M * 2048
    float* ygate   = delta + M * 2048;         // M * 2048
    float* tpre    = xz;                       // M * 1024, reuses dead xz region

    const dim3 blk(256);

    // 1. xz = x @ W_in + b_in                     (M=2048, N=4096, K=1024)
    gemm_f32<0><<<dim3(4096 / 64, 2048 / 64), blk, 0, stream>>>(
        x, W_in, b_in, nullptr, xz, 2048, 4096, 1024);

    // 2. depthwise causal conv + SiLU
    conv_silu<<<dim3((unsigned)(M * (DINNER / 4) / 256)), blk, 0, stream>>>(
        xz, conv_w, conv_b, x_conv);

    // 3. BC = x_conv @ W_xp + b_xp                (N=32)
    xproj_kernel<<<dim3((unsigned)M), blk, 0, stream>>>(x_conv, W_xp, b_xp, BC);

    // 4. delta = softplus(x_conv @ W_dt + b_dt)   (M=2048, N=2048, K=2048)
    gemm_f32<1><<<dim3(2048 / 64, 2048 / 64), blk, 0, stream>>>(
        x_conv, W_dt, b_dt, nullptr, delta, 2048, 2048, 2048);

    // 5. selective scan + D_skip + z-gate
    scan_kernel<<<dim3(B_SZ * (DINNER / 16)), blk, 0, stream>>>(
        delta, x_conv, BC, A_log, D_skip, xz, ygate);

    // 6. tpre = ygate @ W_out + b_out + x         (M=2048, N=1024, K=2048)
    gemm_f32<2><<<dim3(1024 / 64, 2048 / 64), blk, 0, stream>>>(
        ygate, W_out, b_out, x, tpre, 2048, 1024, 2048);

    // 7. LayerNorm
    layernorm_kernel<<<dim3((unsigned)M), blk, 0, stream>>>(tpre, alpha, beta, out);
}

// Round 2
// 523.707 us; speedup vs baseline: 1.8529x; 1.8529x over previous
//
#include <hip/hip_runtime.h>
#include <math.h>

#define B_SZ    2
#define L_SEQ   1024
#define DMODEL  1024
#define DINNER  2048
#define DSTATE  16
#define EPSV    1e-6f

typedef short  bf16x8  __attribute__((ext_vector_type(8)));
typedef float  floatx4 __attribute__((ext_vector_type(4)));

__device__ __forceinline__ unsigned short f2bf(float f) {
    unsigned int u = __float_as_uint(f);
    unsigned int r = (u + 0x7FFFu + ((u >> 16) & 1u)) >> 16;
    return (unsigned short)r;
}

__device__ __forceinline__ void load16_to_lds(const void* g, void* l) {
    __builtin_amdgcn_global_load_lds(
        (const __attribute__((address_space(1))) void*)g,
        (__attribute__((address_space(3))) void*)l, 16, 0, 0);
}

// ---------------------------------------------------------------------------
// fp32 -> bf16 elementwise cast (4 elems/thread)
// ---------------------------------------------------------------------------
__global__ __launch_bounds__(256) void cast_bf16_kernel(
    const float* __restrict__ in, unsigned short* __restrict__ out, int n4)
{
    int i = blockIdx.x * 256 + threadIdx.x;
    if (i >= n4) return;
    float4 v = ((const float4*)in)[i];
    ushort4 o = { f2bf(v.x), f2bf(v.y), f2bf(v.z), f2bf(v.w) };
    ((ushort4*)out)[i] = o;
}

// ---------------------------------------------------------------------------
// W (KxN fp32, row-major) -> Wt (NxK bf16, row-major)
// 32x32 tiles, 256 threads (8 rows x 32 cols, 4 iters).
// ---------------------------------------------------------------------------
__global__ __launch_bounds__(256) void transpose_cast(
    const float* __restrict__ W, unsigned short* __restrict__ Wt, int K, int N)
{
    __shared__ float tile[32][33];
    const int n0 = blockIdx.x * 32;
    const int k0 = blockIdx.y * 32;
    const int c = threadIdx.x & 31;
    const int r = threadIdx.x >> 5;
#pragma unroll
    for (int i = 0; i < 4; ++i)
        tile[r + 8 * i][c] = W[(size_t)(k0 + r + 8 * i) * N + n0 + c];
    __syncthreads();
#pragma unroll
    for (int i = 0; i < 4; ++i)
        Wt[(size_t)(n0 + r + 8 * i) * K + k0 + c] = f2bf(tile[c][r + 8 * i]);
}

// ---------------------------------------------------------------------------
// bf16 MFMA GEMM: C(f32) = epilogue(A @ Bt^T + bias)
// A: MxK bf16 row-major; Bt: NxK bf16 row-major (pre-transposed weights).
// 128x128 tile, BK=32, 256 threads = 4 waves, each wave a 64x64 quadrant
// (4x4 grid of 16x16x32 MFMA). global_load_lds width=16 staging.
// MODE 0: +bias; MODE 1: softplus(+bias); MODE 2: +bias + resid.
// Requires M%128==0, N%128==0, K%32==0.
// ---------------------------------------------------------------------------
template <int MODE>
__global__ __launch_bounds__(256) void gemm_bf16(
    const unsigned short* __restrict__ A, const unsigned short* __restrict__ Bt,
    const float* __restrict__ bias, const float* __restrict__ resid,
    float* __restrict__ C, int M, int N, int K)
{
    __shared__ unsigned short As[128 * 32];
    __shared__ unsigned short Bs[128 * 32];

    const int tid  = threadIdx.x;
    const int wave = tid >> 6;
    const int lane = tid & 63;
    const int m0 = blockIdx.y * 128;
    const int n0 = blockIdx.x * 128;
    const int wm = (wave >> 1) * 64;   // wave's row quadrant
    const int wn = (wave & 1) * 64;    // wave's col quadrant

    // staging: thread t covers row t/4 (of 64), k-chunk (t%4)*8
    const int srow = tid >> 2;
    const int sk8  = (tid & 3) * 8;

    // fragment coords
    const int fr = lane & 15;          // row (A) / col (B) within 16
    const int fq = (lane >> 4) * 8;    // k offset of the 8 held elems

    floatx4 acc[4][4] = {};

    for (int kt = 0; kt < K; kt += 32) {
        const unsigned short* Ag0 = A  + (size_t)(m0 + srow) * K + kt + sk8;
        const unsigned short* Ag1 = A  + (size_t)(m0 + 64 + srow) * K + kt + sk8;
        const unsigned short* Bg0 = Bt + (size_t)(n0 + srow) * K + kt + sk8;
        const unsigned short* Bg1 = Bt + (size_t)(n0 + 64 + srow) * K + kt + sk8;
        __syncthreads();   // prior compute finished reading LDS
        load16_to_lds(Ag0, &As[(wave * 16) * 32]);
        load16_to_lds(Ag1, &As[(64 + wave * 16) * 32]);
        load16_to_lds(Bg0, &Bs[(wave * 16) * 32]);
        load16_to_lds(Bg1, &Bs[(64 + wave * 16) * 32]);
        __syncthreads();   // compiler drains vmcnt before barrier

        bf16x8 af[4], bfr[4];
#pragma unroll
        for (int i = 0; i < 4; ++i)
            af[i] = *(const bf16x8*)&As[(wm + i * 16 + fr) * 32 + fq];
#pragma unroll
        for (int j = 0; j < 4; ++j)
            bfr[j] = *(const bf16x8*)&Bs[(wn + j * 16 + fr) * 32 + fq];
#pragma unroll
        for (int i = 0; i < 4; ++i)
#pragma unroll
            for (int j = 0; j < 4; ++j)
                acc[i][j] = __builtin_amdgcn_mfma_f32_16x16x32_bf16(
                    af[i], bfr[j], acc[i][j], 0, 0, 0);
    }

    // C/D layout: col = lane&15, row = (lane>>4)*4 + reg
    const int rq = (lane >> 4) * 4;
#pragma unroll
    for (int i = 0; i < 4; ++i) {
#pragma unroll
        for (int j = 0; j < 4; ++j) {
            const int col = n0 + wn + j * 16 + fr;
            const float bv = bias[col];
#pragma unroll
            for (int r = 0; r < 4; ++r) {
                const int row = m0 + wm + i * 16 + rq + r;
                float v = acc[i][j][r] + bv;
                if (MODE == 1) {
                    v = (v > 20.f) ? v : log1pf(__expf(v));
                } else if (MODE == 2) {
                    v += resid[(size_t)row * N + col];
                }
                C[(size_t)row * N + col] = v;
            }
        }
    }
}

// ---------------------------------------------------------------------------
// Depthwise causal conv1d (k=4) + SiLU; writes fp32 and bf16 copies.
// ---------------------------------------------------------------------------
__global__ __launch_bounds__(256) void conv_silu(
    const float* __restrict__ xz, const float* __restrict__ conv_w,
    const float* __restrict__ conv_b, float* __restrict__ x_conv,
    unsigned short* __restrict__ x_conv_bf)
{
    const int idx = blockIdx.x * 256 + threadIdx.x;
    const int c4  = (idx & (DINNER / 4 - 1)) << 2;
    const int row = idx >> 9;
    const int l   = row & (L_SEQ - 1);

    float4 w0 = *(const float4*)&conv_w[(c4 + 0) * 4];
    float4 w1 = *(const float4*)&conv_w[(c4 + 1) * 4];
    float4 w2 = *(const float4*)&conv_w[(c4 + 2) * 4];
    float4 w3 = *(const float4*)&conv_w[(c4 + 3) * 4];
    const float wt[4][4] = {{w0.x, w0.y, w0.z, w0.w},
                            {w1.x, w1.y, w1.z, w1.w},
                            {w2.x, w2.y, w2.z, w2.w},
                            {w3.x, w3.y, w3.z, w3.w}};
    float4 cb = *(const float4*)&conv_b[c4];
    float acc[4] = {cb.x, cb.y, cb.z, cb.w};

#pragma unroll
    for (int h = 0; h < 4; ++h) {
        const int lsrc = l - 3 + h;
        if (lsrc >= 0) {
            float4 xv = *(const float4*)&xz[(size_t)(row - 3 + h) * (2 * DINNER) + c4];
            acc[0] += xv.x * wt[0][h];
            acc[1] += xv.y * wt[1][h];
            acc[2] += xv.z * wt[2][h];
            acc[3] += xv.w * wt[3][h];
        }
    }
    float4 o;
    o.x = acc[0] / (1.f + __expf(-acc[0]));
    o.y = acc[1] / (1.f + __expf(-acc[1]));
    o.z = acc[2] / (1.f + __expf(-acc[2]));
    o.w = acc[3] / (1.f + __expf(-acc[3]));
    *(float4*)&x_conv[(size_t)row * DINNER + c4] = o;
    ushort4 ob = { f2bf(o.x), f2bf(o.y), f2bf(o.z), f2bf(o.w) };
    *(ushort4*)&x_conv_bf[(size_t)row * DINNER + c4] = ob;
}

// ---------------------------------------------------------------------------
// x_proj: BC[row][0:32] = x_conv[row] @ W_xp + b_xp  (N=32, K=2048)
// ---------------------------------------------------------------------------
__global__ __launch_bounds__(256) void xproj_kernel(
    const float* __restrict__ x_conv, const float* __restrict__ W_xp,
    const float* __restrict__ b_xp, float* __restrict__ BC)
{
    __shared__ float red[8][32];
    const int row = blockIdx.x;
    const int n = threadIdx.x & 31;
    const int g = threadIdx.x >> 5;
    const float* xr = x_conv + (size_t)row * DINNER;
    float p = 0.f;
    const int k0 = g * (DINNER / 8);
#pragma unroll 8
    for (int k = k0; k < k0 + DINNER / 8; ++k)
        p = fmaf(xr[k], W_xp[k * 32 + n], p);
    red[g][n] = p;
    __syncthreads();
    if (threadIdx.x < 32) {
        float ssum = b_xp[n];
#pragma unroll
        for (int gg = 0; gg < 8; ++gg) ssum += red[gg][n];
        BC[(size_t)row * 32 + n] = ssum;
    }
}

// ---------------------------------------------------------------------------
// Selective scan + D_skip + z-gate; emits bf16 gated output for the out GEMM.
// Block: 256 threads = 16 channels x 16 states. Grid: B * DINNER/16.
// ---------------------------------------------------------------------------
__global__ __launch_bounds__(256) void scan_kernel(
    const float* __restrict__ delta, const float* __restrict__ x_conv,
    const float* __restrict__ BC, const float* __restrict__ A_log,
    const float* __restrict__ D_skip, const float* __restrict__ xz,
    unsigned short* __restrict__ y_bf)
{
    __shared__ float sD[64][16];
    __shared__ float sX[64][16];
    __shared__ float sBC[64][32];
    __shared__ float sY[64][16];

    const int tid = threadIdx.x;
    const int b  = blockIdx.x >> 7;
    const int d0 = (blockIdx.x & 127) << 4;
    const int g = tid >> 4;
    const int s = tid & 15;
    const int d = d0 + g;

    const float Av  = -__expf(A_log[d * DSTATE + s]);
    const float Dsk = D_skip[d];
    float h = 0.f;

    const int jj = tid >> 2;
    const int q4 = (tid & 3) << 2;

    for (int l0 = 0; l0 < L_SEQ; l0 += 64) {
        const size_t rbase = (size_t)(b * L_SEQ + l0 + jj);
        float4 dv  = *(const float4*)&delta[rbase * DINNER + d0 + q4];
        float4 xv  = *(const float4*)&x_conv[rbase * DINNER + d0 + q4];
        float4 bc0 = *(const float4*)&BC[rbase * 32 + q4];
        float4 bc1 = *(const float4*)&BC[rbase * 32 + 16 + q4];
        __syncthreads();
        *(float4*)&sD[jj][q4] = dv;
        *(float4*)&sX[jj][q4] = xv;
        *(float4*)&sBC[jj][q4] = bc0;
        *(float4*)&sBC[jj][16 + q4] = bc1;
        __syncthreads();

#pragma unroll 4
        for (int j = 0; j < 64; ++j) {
            const float dl = sD[j][g];
            const float xc = sX[j][g];
            const float bv = sBC[j][s];
            const float cv = sBC[j][16 + s];
            h = __expf(dl * Av) * h + dl * xc * bv;
            float p = h * cv;
            p += __shfl_xor(p, 1);
            p += __shfl_xor(p, 2);
            p += __shfl_xor(p, 4);
            p += __shfl_xor(p, 8);
            if (s == 0) sY[j][g] = p + Dsk * xc;
        }
        __syncthreads();

        {
            float4 zv = *(const float4*)&xz[rbase * (2 * DINNER) + DINNER + d0 + q4];
            float4 yv = *(const float4*)&sY[jj][q4];
            float4 o;
            o.x = yv.x * (zv.x / (1.f + __expf(-zv.x)));
            o.y = yv.y * (zv.y / (1.f + __expf(-zv.y)));
            o.z = yv.z * (zv.z / (1.f + __expf(-zv.z)));
            o.w = yv.w * (zv.w / (1.f + __expf(-zv.w)));
            ushort4 ob = { f2bf(o.x), f2bf(o.y), f2bf(o.z), f2bf(o.w) };
            *(ushort4*)&y_bf[rbase * DINNER + d0 + q4] = ob;
        }
    }
}

// ---------------------------------------------------------------------------
// Row LayerNorm: unbiased variance (N-1), eps added to std.
// ---------------------------------------------------------------------------
__global__ __launch_bounds__(256) void layernorm_kernel(
    const float* __restrict__ t, const float* __restrict__ alpha,
    const float* __restrict__ beta, float* __restrict__ out)
{
    __shared__ float sred[4];
    __shared__ float sred2[4];
    const int row = blockIdx.x;
    const int tid = threadIdx.x;
    const float* r = t + (size_t)row * DMODEL;

    float4 v = *(const float4*)&r[tid * 4];
    float lsum = v.x + v.y + v.z + v.w;
#pragma unroll
    for (int m = 1; m < 64; m <<= 1) lsum += __shfl_xor(lsum, m);
    if ((tid & 63) == 0) sred[tid >> 6] = lsum;
    __syncthreads();
    const float mean = (sred[0] + sred[1] + sred[2] + sred[3]) * (1.f / DMODEL);

    const float dx = v.x - mean, dy = v.y - mean, dz = v.z - mean, dw = v.w - mean;
    float ls2 = dx * dx + dy * dy + dz * dz + dw * dw;
#pragma unroll
    for (int m = 1; m < 64; m <<= 1) ls2 += __shfl_xor(ls2, m);
    if ((tid & 63) == 0) sred2[tid >> 6] = ls2;
    __syncthreads();
    const float var = (sred2[0] + sred2[1] + sred2[2] + sred2[3]) * (1.f / (DMODEL - 1));
    const float inv = 1.f / (sqrtf(var) + EPSV);

    float4 a4 = *(const float4*)&alpha[tid * 4];
    float4 b4 = *(const float4*)&beta[tid * 4];
    float4 o;
    o.x = a4.x * dx * inv + b4.x;
    o.y = a4.y * dy * inv + b4.y;
    o.z = a4.z * dz * inv + b4.z;
    o.w = a4.w * dw * inv + b4.w;
    *(float4*)&out[(size_t)row * DMODEL + tid * 4] = o;
}

// ---------------------------------------------------------------------------
extern "C" void kernel_launch(void* const* d_in, const int* in_sizes, int n_in,
                              void* d_out, int out_size, void* d_ws, size_t ws_size,
                              hipStream_t stream)
{
    const float* x      = (const float*)d_in[0];
    const float* W_in   = (const float*)d_in[1];
    const float* b_in   = (const float*)d_in[2];
    const float* conv_w = (const float*)d_in[3];
    const float* conv_b = (const float*)d_in[4];
    const float* W_xp   = (const float*)d_in[5];
    const float* b_xp   = (const float*)d_in[6];
    const float* W_dt   = (const float*)d_in[7];
    const float* b_dt   = (const float*)d_in[8];
    const float* A_log  = (const float*)d_in[9];
    const float* D_skip = (const float*)d_in[10];
    const float* W_out  = (const float*)d_in[11];
    const float* b_out  = (const float*)d_in[12];
    const float* alpha  = (const float*)d_in[13];
    const float* beta   = (const float*)d_in[14];
    float* out = (float*)d_out;

    const size_t M = (size_t)B_SZ * L_SEQ;  // 2048 rows
    char* ws = (char*)d_ws;
    // fp32 regions
    float* xz      = (float*)(ws + 0);                  // 32 MB (reused as tpre)
    float* x_conv  = (float*)(ws + (32u << 20));        // 16 MB
    float* delta   = (float*)(ws + (48u << 20));        // 16 MB
    float* BC      = (float*)(ws + (64u << 20));        // 0.5 MB
    // bf16 regions
    unsigned short* x_bf       = (unsigned short*)(ws + (64u << 20) + (512u << 10)); // 4 MB
    unsigned short* W_in_t     = (unsigned short*)(ws + (69u << 20));  // 8 MB
    unsigned short* W_dt_t     = (unsigned short*)(ws + (77u << 20));  // 8 MB
    unsigned short* W_out_t    = (unsigned short*)(ws + (85u << 20));  // 4 MB
    unsigned short* x_conv_bf  = (unsigned short*)(ws + (89u << 20));  // 8 MB
    unsigned short* ygate_bf   = (unsigned short*)(ws + (77u << 20));  // reuse W_dt_t (dead after delta GEMM)
    float* tpre = xz;  // reuse xz region (dead after scan)

    const dim3 blk(256);

    // 0. casts / transposes
    cast_bf16_kernel<<<dim3((unsigned)(M * DMODEL / 4 / 256)), blk, 0, stream>>>(
        x, x_bf, (int)(M * DMODEL / 4));
    transpose_cast<<<dim3(2 * DINNER / 32, DMODEL / 32), blk, 0, stream>>>(
        W_in, W_in_t, DMODEL, 2 * DINNER);
    transpose_cast<<<dim3(DINNER / 32, DINNER / 32), blk, 0, stream>>>(
        W_dt, W_dt_t, DINNER, DINNER);
    transpose_cast<<<dim3(DMODEL / 32, DINNER / 32), blk, 0, stream>>>(
        W_out, W_out_t, DINNER, DMODEL);

    // 1. xz = x @ W_in + b_in        (2048 x 4096 x 1024)
    gemm_bf16<0><<<dim3(4096 / 128, 2048 / 128), blk, 0, stream>>>(
        x_bf, W_in_t, b_in, nullptr, xz, 2048, 4096, 1024);

    // 2. depthwise causal conv + SiLU (+ bf16 copy)
    conv_silu<<<dim3((unsigned)(M * (DINNER / 4) / 256)), blk, 0, stream>>>(
        xz, conv_w, conv_b, x_conv, x_conv_bf);

    // 3. BC = x_conv @ W_xp + b_xp   (N=32)
    xproj_kernel<<<dim3((unsigned)M), blk, 0, stream>>>(x_conv, W_xp, b_xp, BC);

    // 4. delta = softplus(x_conv @ W_dt + b_dt)   (2048 x 2048 x 2048)
    gemm_bf16<1><<<dim3(2048 / 128, 2048 / 128), blk, 0, stream>>>(
        x_conv_bf, W_dt_t, b_dt, nullptr, delta, 2048, 2048, 2048);

    // 5. selective scan + D_skip + z-gate -> bf16
    scan_kernel<<<dim3(B_SZ * (DINNER / 16)), blk, 0, stream>>>(
        delta, x_conv, BC, A_log, D_skip, xz, ygate_bf);

    // 6. tpre = ygate @ W_out + b_out + x         (2048 x 1024 x 2048)
    gemm_bf16<2><<<dim3(1024 / 128, 2048 / 128), blk, 0, stream>>>(
        ygate_bf, W_out_t, b_out, x, tpre, 2048, 1024, 2048);

    // 7. LayerNorm
    layernorm_kernel<<<dim3((unsigned)M), blk, 0, stream>>>(tpre, alpha, beta, out);
}

// Round 3
// 368.207 us; speedup vs baseline: 2.6354x; 1.4223x over previous
//
#include <hip/hip_runtime.h>
#include <math.h>

#define B_SZ    2
#define L_SEQ   1024
#define DMODEL  1024
#define DINNER  2048
#define DSTATE  16
#define EPSV    1e-6f

// scan decomposition
#define CCH 32                 // chunks over L
#define CS  (L_SEQ / CCH)      // 32 steps per chunk
#define DT  16                 // channels per block

typedef short  bf16x8  __attribute__((ext_vector_type(8)));
typedef float  floatx4 __attribute__((ext_vector_type(4)));

__device__ __forceinline__ unsigned short f2bf(float f) {
    unsigned int u = __float_as_uint(f);
    unsigned int r = (u + 0x7FFFu + ((u >> 16) & 1u)) >> 16;
    return (unsigned short)r;
}

__device__ __forceinline__ void load16_to_lds(const void* g, void* l) {
    __builtin_amdgcn_global_load_lds(
        (const __attribute__((address_space(1))) void*)g,
        (__attribute__((address_space(3))) void*)l, 16, 0, 0);
}

// ---------------------------------------------------------------------------
// fp32 -> bf16 elementwise cast (4 elems/thread)
// ---------------------------------------------------------------------------
__global__ __launch_bounds__(256) void cast_bf16_kernel(
    const float* __restrict__ in, unsigned short* __restrict__ out, int n4)
{
    int i = blockIdx.x * 256 + threadIdx.x;
    if (i >= n4) return;
    float4 v = ((const float4*)in)[i];
    ushort4 o = { f2bf(v.x), f2bf(v.y), f2bf(v.z), f2bf(v.w) };
    ((ushort4*)out)[i] = o;
}

// ---------------------------------------------------------------------------
// W (KxN fp32, row-major) -> Wt (NxK bf16, row-major)
// ---------------------------------------------------------------------------
__global__ __launch_bounds__(256) void transpose_cast(
    const float* __restrict__ W, unsigned short* __restrict__ Wt, int K, int N)
{
    __shared__ float tile[32][33];
    const int n0 = blockIdx.x * 32;
    const int k0 = blockIdx.y * 32;
    const int c = threadIdx.x & 31;
    const int r = threadIdx.x >> 5;
#pragma unroll
    for (int i = 0; i < 4; ++i)
        tile[r + 8 * i][c] = W[(size_t)(k0 + r + 8 * i) * N + n0 + c];
    __syncthreads();
#pragma unroll
    for (int i = 0; i < 4; ++i)
        Wt[(size_t)(n0 + r + 8 * i) * K + k0 + c] = f2bf(tile[c][r + 8 * i]);
}

// ---------------------------------------------------------------------------
// bf16 MFMA GEMM: C(f32) = epilogue(A @ Bt^T + bias)
// 128x128 tile, BK=32, 4 waves, 16x16x32 MFMA, global_load_lds staging.
// MODE 0: +bias; MODE 1: softplus(+bias); MODE 2: +bias + resid.
// ---------------------------------------------------------------------------
template <int MODE>
__global__ __launch_bounds__(256) void gemm_bf16(
    const unsigned short* __restrict__ A, const unsigned short* __restrict__ Bt,
    const float* __restrict__ bias, const float* __restrict__ resid,
    float* __restrict__ C, int M, int N, int K)
{
    __shared__ unsigned short As[128 * 32];
    __shared__ unsigned short Bs[128 * 32];

    const int tid  = threadIdx.x;
    const int wave = tid >> 6;
    const int lane = tid & 63;
    const int m0 = blockIdx.y * 128;
    const int n0 = blockIdx.x * 128;
    const int wm = (wave >> 1) * 64;
    const int wn = (wave & 1) * 64;

    const int srow = tid >> 2;
    const int sk8  = (tid & 3) * 8;

    const int fr = lane & 15;
    const int fq = (lane >> 4) * 8;

    floatx4 acc[4][4] = {};

    for (int kt = 0; kt < K; kt += 32) {
        const unsigned short* Ag0 = A  + (size_t)(m0 + srow) * K + kt + sk8;
        const unsigned short* Ag1 = A  + (size_t)(m0 + 64 + srow) * K + kt + sk8;
        const unsigned short* Bg0 = Bt + (size_t)(n0 + srow) * K + kt + sk8;
        const unsigned short* Bg1 = Bt + (size_t)(n0 + 64 + srow) * K + kt + sk8;
        __syncthreads();
        load16_to_lds(Ag0, &As[(wave * 16) * 32]);
        load16_to_lds(Ag1, &As[(64 + wave * 16) * 32]);
        load16_to_lds(Bg0, &Bs[(wave * 16) * 32]);
        load16_to_lds(Bg1, &Bs[(64 + wave * 16) * 32]);
        __syncthreads();

        bf16x8 af[4], bfr[4];
#pragma unroll
        for (int i = 0; i < 4; ++i)
            af[i] = *(const bf16x8*)&As[(wm + i * 16 + fr) * 32 + fq];
#pragma unroll
        for (int j = 0; j < 4; ++j)
            bfr[j] = *(const bf16x8*)&Bs[(wn + j * 16 + fr) * 32 + fq];
#pragma unroll
        for (int i = 0; i < 4; ++i)
#pragma unroll
            for (int j = 0; j < 4; ++j)
                acc[i][j] = __builtin_amdgcn_mfma_f32_16x16x32_bf16(
                    af[i], bfr[j], acc[i][j], 0, 0, 0);
    }

    const int rq = (lane >> 4) * 4;
#pragma unroll
    for (int i = 0; i < 4; ++i) {
#pragma unroll
        for (int j = 0; j < 4; ++j) {
            const int col = n0 + wn + j * 16 + fr;
            const float bv = bias[col];
#pragma unroll
            for (int r = 0; r < 4; ++r) {
                const int row = m0 + wm + i * 16 + rq + r;
                float v = acc[i][j][r] + bv;
                if (MODE == 1) {
                    v = (v > 20.f) ? v : log1pf(__expf(v));
                } else if (MODE == 2) {
                    v += resid[(size_t)row * N + col];
                }
                C[(size_t)row * N + col] = v;
            }
        }
    }
}

// ---------------------------------------------------------------------------
// Depthwise causal conv1d (k=4) + SiLU; writes fp32 and bf16 copies.
// ---------------------------------------------------------------------------
__global__ __launch_bounds__(256) void conv_silu(
    const float* __restrict__ xz, const float* __restrict__ conv_w,
    const float* __restrict__ conv_b, float* __restrict__ x_conv,
    unsigned short* __restrict__ x_conv_bf)
{
    const int idx = blockIdx.x * 256 + threadIdx.x;
    const int c4  = (idx & (DINNER / 4 - 1)) << 2;
    const int row = idx >> 9;
    const int l   = row & (L_SEQ - 1);

    float4 w0 = *(const float4*)&conv_w[(c4 + 0) * 4];
    float4 w1 = *(const float4*)&conv_w[(c4 + 1) * 4];
    float4 w2 = *(const float4*)&conv_w[(c4 + 2) * 4];
    float4 w3 = *(const float4*)&conv_w[(c4 + 3) * 4];
    const float wt[4][4] = {{w0.x, w0.y, w0.z, w0.w},
                            {w1.x, w1.y, w1.z, w1.w},
                            {w2.x, w2.y, w2.z, w2.w},
                            {w3.x, w3.y, w3.z, w3.w}};
    float4 cb = *(const float4*)&conv_b[c4];
    float acc[4] = {cb.x, cb.y, cb.z, cb.w};

#pragma unroll
    for (int h = 0; h < 4; ++h) {
        const int lsrc = l - 3 + h;
        if (lsrc >= 0) {
            float4 xv = *(const float4*)&xz[(size_t)(row - 3 + h) * (2 * DINNER) + c4];
            acc[0] += xv.x * wt[0][h];
            acc[1] += xv.y * wt[1][h];
            acc[2] += xv.z * wt[2][h];
            acc[3] += xv.w * wt[3][h];
        }
    }
    float4 o;
    o.x = acc[0] / (1.f + __expf(-acc[0]));
    o.y = acc[1] / (1.f + __expf(-acc[1]));
    o.z = acc[2] / (1.f + __expf(-acc[2]));
    o.w = acc[3] / (1.f + __expf(-acc[3]));
    *(float4*)&x_conv[(size_t)row * DINNER + c4] = o;
    ushort4 ob = { f2bf(o.x), f2bf(o.y), f2bf(o.z), f2bf(o.w) };
    *(ushort4*)&x_conv_bf[(size_t)row * DINNER + c4] = ob;
}

// ---------------------------------------------------------------------------
// x_proj: BC[row][0:32] = x_conv[row] @ W_xp + b_xp  (N=32, K=2048)
// ---------------------------------------------------------------------------
__global__ __launch_bounds__(256) void xproj_kernel(
    const float* __restrict__ x_conv, const float* __restrict__ W_xp,
    const float* __restrict__ b_xp, float* __restrict__ BC)
{
    __shared__ float red[8][32];
    const int row = blockIdx.x;
    const int n = threadIdx.x & 31;
    const int g = threadIdx.x >> 5;
    const float* xr = x_conv + (size_t)row * DINNER;
    float p = 0.f;
    const int k0 = g * (DINNER / 8);
#pragma unroll 8
    for (int k = k0; k < k0 + DINNER / 8; ++k)
        p = fmaf(xr[k], W_xp[k * 32 + n], p);
    red[g][n] = p;
    __syncthreads();
    if (threadIdx.x < 32) {
        float ssum = b_xp[n];
#pragma unroll
        for (int gg = 0; gg < 8; ++gg) ssum += red[gg][n];
        BC[(size_t)row * 32 + n] = ssum;
    }
}

// ---------------------------------------------------------------------------
// Chunked two-pass selective scan, states-in-registers, no cross-lane ops.
// Block: 512 threads = 16 channels (dl) x 32 chunks (c). Grid: B * DINNER/16.
// Pass 1: per-chunk summary (A_prod via exp2(A*sum_delta), h_end).
// Combine: 32-step sequential merge in LDS -> per-chunk h0.
// Pass 2: rescan with true h0, fuse D_skip + silu(z) gate, emit bf16.
// ---------------------------------------------------------------------------
__global__ __launch_bounds__(512) void scan_kernel(
    const float* __restrict__ delta, const float* __restrict__ x_conv,
    const float* __restrict__ BC, const float* __restrict__ A_log,
    const float* __restrict__ D_skip, const float* __restrict__ xz,
    unsigned short* __restrict__ y_bf)
{
    __shared__ float sA[DSTATE][CCH][DT];   // chunk A-products
    __shared__ float sH[DSTATE][CCH][DT];   // chunk h_end, then h0

    const int tid = threadIdx.x;
    const int dl  = tid & (DT - 1);
    const int c   = tid >> 4;               // 0..31
    const int b   = blockIdx.x >> 7;
    const int d0  = (blockIdx.x & 127) * DT;
    const int d   = d0 + dl;

    // A in log2 domain: dA = exp2(delta * Al[s])
    float Al[DSTATE];
#pragma unroll
    for (int s = 0; s < DSTATE; ++s)
        Al[s] = -__expf(A_log[d * DSTATE + s]) * 1.44269504f;
    const float Dsk = D_skip[d];

    float h[DSTATE];
#pragma unroll
    for (int s = 0; s < DSTATE; ++s) h[s] = 0.f;
    float dsum = 0.f;
    const int l0 = c * CS;

    // ---- pass 1: chunk summaries from h=0 ----
    for (int j = 0; j < CS; ++j) {
        const size_t r = (size_t)(b * L_SEQ + l0 + j);
        const float dt = delta[r * DINNER + d];
        const float xc = x_conv[r * DINNER + d];
        float Bv[DSTATE];
        *(float4*)&Bv[0]  = *(const float4*)&BC[r * 32 + 0];
        *(float4*)&Bv[4]  = *(const float4*)&BC[r * 32 + 4];
        *(float4*)&Bv[8]  = *(const float4*)&BC[r * 32 + 8];
        *(float4*)&Bv[12] = *(const float4*)&BC[r * 32 + 12];
        dsum += dt;
        const float dlx = dt * xc;
#pragma unroll
        for (int s = 0; s < DSTATE; ++s) {
            const float e = exp2f(dt * Al[s]);
            h[s] = e * h[s] + dlx * Bv[s];
        }
    }
#pragma unroll
    for (int s = 0; s < DSTATE; ++s) {
        sH[s][c][dl] = h[s];
        sA[s][c][dl] = exp2f(Al[s] * dsum);
    }
    __syncthreads();

    // ---- combine: sequential over chunks, parallel over (dl, s) ----
    if (tid < DSTATE * DT) {
        const int dl2 = tid & (DT - 1);
        const int s2  = tid >> 4;
        float hh = 0.f;
#pragma unroll
        for (int c2 = 0; c2 < CCH; ++c2) {
            const float a  = sA[s2][c2][dl2];
            const float he = sH[s2][c2][dl2];
            sH[s2][c2][dl2] = hh;          // h0 entering chunk c2
            hh = a * hh + he;
        }
    }
    __syncthreads();

#pragma unroll
    for (int s = 0; s < DSTATE; ++s) h[s] = sH[s][c][dl];

    // ---- pass 2: rescan with true h0, produce gated bf16 output ----
    for (int j = 0; j < CS; ++j) {
        const size_t r = (size_t)(b * L_SEQ + l0 + j);
        const float dt = delta[r * DINNER + d];
        const float xc = x_conv[r * DINNER + d];
        const float z  = xz[r * (2 * DINNER) + DINNER + d];
        float Bv[DSTATE], Cv[DSTATE];
        *(float4*)&Bv[0]  = *(const float4*)&BC[r * 32 + 0];
        *(float4*)&Bv[4]  = *(const float4*)&BC[r * 32 + 4];
        *(float4*)&Bv[8]  = *(const float4*)&BC[r * 32 + 8];
        *(float4*)&Bv[12] = *(const float4*)&BC[r * 32 + 12];
        *(float4*)&Cv[0]  = *(const float4*)&BC[r * 32 + 16];
        *(float4*)&Cv[4]  = *(const float4*)&BC[r * 32 + 20];
        *(float4*)&Cv[8]  = *(const float4*)&BC[r * 32 + 24];
        *(float4*)&Cv[12] = *(const float4*)&BC[r * 32 + 28];
        const float dlx = dt * xc;
        float y = Dsk * xc;
#pragma unroll
        for (int s = 0; s < DSTATE; ++s) {
            const float e = exp2f(dt * Al[s]);
            h[s] = e * h[s] + dlx * Bv[s];
            y += h[s] * Cv[s];
        }
        const float g = z / (1.f + __expf(-z));
        y_bf[r * DINNER + d] = f2bf(y * g);
    }
}

// ---------------------------------------------------------------------------
// Row LayerNorm: unbiased variance (N-1), eps added to std.
// ---------------------------------------------------------------------------
__global__ __launch_bounds__(256) void layernorm_kernel(
    const float* __restrict__ t, const float* __restrict__ alpha,
    const float* __restrict__ beta, float* __restrict__ out)
{
    __shared__ float sred[4];
    __shared__ float sred2[4];
    const int row = blockIdx.x;
    const int tid = threadIdx.x;
    const float* r = t + (size_t)row * DMODEL;

    float4 v = *(const float4*)&r[tid * 4];
    float lsum = v.x + v.y + v.z + v.w;
#pragma unroll
    for (int m = 1; m < 64; m <<= 1) lsum += __shfl_xor(lsum, m);
    if ((tid & 63) == 0) sred[tid >> 6] = lsum;
    __syncthreads();
    const float mean = (sred[0] + sred[1] + sred[2] + sred[3]) * (1.f / DMODEL);

    const float dx = v.x - mean, dy = v.y - mean, dz = v.z - mean, dw = v.w - mean;
    float ls2 = dx * dx + dy * dy + dz * dz + dw * dw;
#pragma unroll
    for (int m = 1; m < 64; m <<= 1) ls2 += __shfl_xor(ls2, m);
    if ((tid & 63) == 0) sred2[tid >> 6] = ls2;
    __syncthreads();
    const float var = (sred2[0] + sred2[1] + sred2[2] + sred2[3]) * (1.f / (DMODEL - 1));
    const float inv = 1.f / (sqrtf(var) + EPSV);

    float4 a4 = *(const float4*)&alpha[tid * 4];
    float4 b4 = *(const float4*)&beta[tid * 4];
    float4 o;
    o.x = a4.x * dx * inv + b4.x;
    o.y = a4.y * dy * inv + b4.y;
    o.z = a4.z * dz * inv + b4.z;
    o.w = a4.w * dw * inv + b4.w;
    *(float4*)&out[(size_t)row * DMODEL + tid * 4] = o;
}

// ---------------------------------------------------------------------------
extern "C" void kernel_launch(void* const* d_in, const int* in_sizes, int n_in,
                              void* d_out, int out_size, void* d_ws, size_t ws_size,
                              hipStream_t stream)
{
    const float* x      = (const float*)d_in[0];
    const float* W_in   = (const float*)d_in[1];
    const float* b_in   = (const float*)d_in[2];
    const float* conv_w = (const float*)d_in[3];
    const float* conv_b = (const float*)d_in[4];
    const float* W_xp   = (const float*)d_in[5];
    const float* b_xp   = (const float*)d_in[6];
    const float* W_dt   = (const float*)d_in[7];
    const float* b_dt   = (const float*)d_in[8];
    const float* A_log  = (const float*)d_in[9];
    const float* D_skip = (const float*)d_in[10];
    const float* W_out  = (const float*)d_in[11];
    const float* b_out  = (const float*)d_in[12];
    const float* alpha  = (const float*)d_in[13];
    const float* beta   = (const float*)d_in[14];
    float* out = (float*)d_out;

    const size_t M = (size_t)B_SZ * L_SEQ;  // 2048 rows
    char* ws = (char*)d_ws;
    float* xz      = (float*)(ws + 0);                  // 32 MB (reused as tpre)
    float* x_conv  = (float*)(ws + (32u << 20));        // 16 MB
    float* delta   = (float*)(ws + (48u << 20));        // 16 MB
    float* BC      = (float*)(ws + (64u << 20));        // 0.5 MB
    unsigned short* x_bf       = (unsigned short*)(ws + (64u << 20) + (512u << 10)); // 4 MB
    unsigned short* W_in_t     = (unsigned short*)(ws + (69u << 20));  // 8 MB
    unsigned short* W_dt_t     = (unsigned short*)(ws + (77u << 20));  // 8 MB
    unsigned short* W_out_t    = (unsigned short*)(ws + (85u << 20));  // 4 MB
    unsigned short* x_conv_bf  = (unsigned short*)(ws + (89u << 20));  // 8 MB
    unsigned short* ygate_bf   = (unsigned short*)(ws + (77u << 20));  // reuse W_dt_t
    float* tpre = xz;

    const dim3 blk(256);

    // 0. casts / transposes
    cast_bf16_kernel<<<dim3((unsigned)(M * DMODEL / 4 / 256)), blk, 0, stream>>>(
        x, x_bf, (int)(M * DMODEL / 4));
    transpose_cast<<<dim3(2 * DINNER / 32, DMODEL / 32), blk, 0, stream>>>(
        W_in, W_in_t, DMODEL, 2 * DINNER);
    transpose_cast<<<dim3(DINNER / 32, DINNER / 32), blk, 0, stream>>>(
        W_dt, W_dt_t, DINNER, DINNER);
    transpose_cast<<<dim3(DMODEL / 32, DINNER / 32), blk, 0, stream>>>(
        W_out, W_out_t, DINNER, DMODEL);

    // 1. xz = x @ W_in + b_in        (2048 x 4096 x 1024)
    gemm_bf16<0><<<dim3(4096 / 128, 2048 / 128), blk, 0, stream>>>(
        x_bf, W_in_t, b_in, nullptr, xz, 2048, 4096, 1024);

    // 2. depthwise causal conv + SiLU (+ bf16 copy)
    conv_silu<<<dim3((unsigned)(M * (DINNER / 4) / 256)), blk, 0, stream>>>(
        xz, conv_w, conv_b, x_conv, x_conv_bf);

    // 3. BC = x_conv @ W_xp + b_xp   (N=32)
    xproj_kernel<<<dim3((unsigned)M), blk, 0, stream>>>(x_conv, W_xp, b_xp, BC);

    // 4. delta = softplus(x_conv @ W_dt + b_dt)   (2048 x 2048 x 2048)
    gemm_bf16<1><<<dim3(2048 / 128, 2048 / 128), blk, 0, stream>>>(
        x_conv_bf, W_dt_t, b_dt, nullptr, delta, 2048, 2048, 2048);

    // 5. chunked two-pass selective scan + D_skip + z-gate -> bf16
    scan_kernel<<<dim3(B_SZ * (DINNER / DT)), dim3(512), 0, stream>>>(
        delta, x_conv, BC, A_log, D_skip, xz, ygate_bf);

    // 6. tpre = ygate @ W_out + b_out + x         (2048 x 1024 x 2048)
    gemm_bf16<2><<<dim3(1024 / 128, 2048 / 128), blk, 0, stream>>>(
        ygate_bf, W_out_t, b_out, x, tpre, 2048, 1024, 2048);

    // 7. LayerNorm
    layernorm_kernel<<<dim3((unsigned)M), blk, 0, stream>>>(tpre, alpha, beta, out);
}

// Round 4
// 314.596 us; speedup vs baseline: 3.0846x; 1.1704x over previous
//
#include <hip/hip_runtime.h>
#include <math.h>

#define B_SZ    2
#define L_SEQ   1024
#define DMODEL  1024
#define DINNER  2048
#define DSTATE  16
#define EPSV    1e-6f

// scan decomposition
#define CCH 32
#define CS  (L_SEQ / CCH)
#define DT  16

typedef short  bf16x8  __attribute__((ext_vector_type(8)));
typedef float  floatx4 __attribute__((ext_vector_type(4)));
typedef unsigned short ushort8v __attribute__((ext_vector_type(8)));

__device__ __forceinline__ unsigned short f2bf(float f) {
    unsigned int u = __float_as_uint(f);
    unsigned int r = (u + 0x7FFFu + ((u >> 16) & 1u)) >> 16;
    return (unsigned short)r;
}

__device__ __forceinline__ void load16_to_lds(const void* g, void* l) {
    __builtin_amdgcn_global_load_lds(
        (const __attribute__((address_space(1))) void*)g,
        (__attribute__((address_space(3))) void*)l, 16, 0, 0);
}

// ---------------------------------------------------------------------------
// fp32 -> bf16 elementwise cast
// ---------------------------------------------------------------------------
__global__ __launch_bounds__(256) void cast_bf16_kernel(
    const float* __restrict__ in, unsigned short* __restrict__ out, int n4)
{
    int i = blockIdx.x * 256 + threadIdx.x;
    if (i >= n4) return;
    float4 v = ((const float4*)in)[i];
    ushort4 o = { f2bf(v.x), f2bf(v.y), f2bf(v.z), f2bf(v.w) };
    ((ushort4*)out)[i] = o;
}

// ---------------------------------------------------------------------------
// W (KxN fp32) -> Wt (NxK bf16)
// ---------------------------------------------------------------------------
__global__ __launch_bounds__(256) void transpose_cast(
    const float* __restrict__ W, unsigned short* __restrict__ Wt, int K, int N)
{
    __shared__ float tile[32][33];
    const int n0 = blockIdx.x * 32;
    const int k0 = blockIdx.y * 32;
    const int c = threadIdx.x & 31;
    const int r = threadIdx.x >> 5;
#pragma unroll
    for (int i = 0; i < 4; ++i)
        tile[r + 8 * i][c] = W[(size_t)(k0 + r + 8 * i) * N + n0 + c];
    __syncthreads();
#pragma unroll
    for (int i = 0; i < 4; ++i)
        Wt[(size_t)(n0 + r + 8 * i) * K + k0 + c] = f2bf(tile[c][r + 8 * i]);
}

// ---------------------------------------------------------------------------
// bf16 MFMA GEMM, double-buffered LDS + xor-swizzled chunk placement.
// TM x TN tile, BK=32, 256 threads = 4 waves. A: MxK, Bt: NxK (both bf16,
// K-contiguous). MODE 0: +bias; 1: softplus(+bias); 2: +bias + resid.
// Swizzle: 16B chunk c of row r is stored at chunk position c ^ ((r>>1)&3);
// staging keeps the wave-contiguous LDS write (content permuted on the
// global-fetch side), fragment ds_read_b128 becomes 2-way (free).
// ---------------------------------------------------------------------------
template <int TM, int TN, int MODE>
__global__ __launch_bounds__(256) void gemm_bf16(
    const unsigned short* __restrict__ A, const unsigned short* __restrict__ Bt,
    const float* __restrict__ bias, const float* __restrict__ resid,
    float* __restrict__ C, int M, int N, int K)
{
    constexpr int NJ = TN / 32;        // mfma cols per wave
    constexpr int WN = TN / 2;         // wave col extent
    constexpr int OPW = (TM + TN) / 64;// staging ops per wave

    __shared__ unsigned short As[2][TM * 32];
    __shared__ unsigned short Bs[2][TN * 32];

    const int tid  = threadIdx.x;
    const int wave = tid >> 6;
    const int lane = tid & 63;
    const int m0 = blockIdx.y * TM;
    const int n0 = blockIdx.x * TN;
    const int wm = (wave >> 1) * 64;
    const int wn = (wave & 1) * WN;

    const int fr = lane & 15;
    const int cq = lane >> 4;                   // 16B chunk wanted (k/8 group)
    const int sw = ((fr >> 1) & 3) ^ cq;        // swizzled chunk position

    const int srl = lane >> 2;                  // staging row within 16
    const int scg = (lane & 3) ^ ((lane >> 3) & 3);  // staged content chunk

    auto stage = [&](int bufi, int kt) {
#pragma unroll
        for (int i = 0; i < OPW; ++i) {
            const int o = wave * OPW + i;       // 16-row op index (uniform)
            const int row = 16 * o + srl;
            if (16 * o < TM) {
                load16_to_lds(A + (size_t)(m0 + row) * K + kt + scg * 8,
                              &As[bufi][16 * o * 32]);
            } else {
                load16_to_lds(Bt + (size_t)(n0 + row - TM) * K + kt + scg * 8,
                              &Bs[bufi][(16 * o - TM) * 32]);
            }
        }
    };

    floatx4 acc[4][NJ] = {};

    stage(0, 0);
    int buf = 0;
    for (int kt = 0; kt < K; kt += 32) {
        __syncthreads();                 // drains vmcnt: buf's tiles are ready
        if (kt + 32 < K) stage(buf ^ 1, kt + 32);   // prefetch overlaps compute

        bf16x8 af[4], bfr[NJ];
#pragma unroll
        for (int i = 0; i < 4; ++i)
            af[i] = *(const bf16x8*)&As[buf][(wm + i * 16 + fr) * 32 + sw * 8];
#pragma unroll
        for (int j = 0; j < NJ; ++j)
            bfr[j] = *(const bf16x8*)&Bs[buf][(wn + j * 16 + fr) * 32 + sw * 8];
#pragma unroll
        for (int i = 0; i < 4; ++i)
#pragma unroll
            for (int j = 0; j < NJ; ++j)
                acc[i][j] = __builtin_amdgcn_mfma_f32_16x16x32_bf16(
                    af[i], bfr[j], acc[i][j], 0, 0, 0);
        buf ^= 1;
    }

    const int rq = (lane >> 4) * 4;
#pragma unroll
    for (int i = 0; i < 4; ++i) {
#pragma unroll
        for (int j = 0; j < NJ; ++j) {
            const int col = n0 + wn + j * 16 + fr;
            const float bv = bias[col];
#pragma unroll
            for (int r = 0; r < 4; ++r) {
                const int row = m0 + wm + i * 16 + rq + r;
                float v = acc[i][j][r] + bv;
                if (MODE == 1) {
                    v = (v > 20.f) ? v : log1pf(__expf(v));
                } else if (MODE == 2) {
                    v += resid[(size_t)row * N + col];
                }
                C[(size_t)row * N + col] = v;
            }
        }
    }
}

// ---------------------------------------------------------------------------
// Fused depthwise causal conv1d(k=4) + SiLU + x_proj.
// Block = 4 rows; 256 threads. Conv: thread = 8 channels per row, result
// kept in LDS. x_proj: thread (g,n) reduces 256 channels for output n,
// reusing one W_xp read for all 4 rows.
// ---------------------------------------------------------------------------
#define CROWS 4
__global__ __launch_bounds__(256) void conv_xproj(
    const float* __restrict__ xz, const float* __restrict__ conv_w,
    const float* __restrict__ conv_b, const float* __restrict__ W_xp,
    const float* __restrict__ b_xp, float* __restrict__ x_conv,
    unsigned short* __restrict__ x_conv_bf, float* __restrict__ BC)
{
    __shared__ float sxc[CROWS][DINNER];   // 32 KB
    __shared__ float red[8][CROWS][32];    // 4 KB

    const int tid = threadIdx.x;
    const int r0 = blockIdx.x * CROWS;
    const int c8 = tid * 8;

    float wt[8][4];
#pragma unroll
    for (int ci = 0; ci < 8; ++ci) {
        float4 w4 = *(const float4*)&conv_w[(c8 + ci) * 4];
        wt[ci][0] = w4.x; wt[ci][1] = w4.y; wt[ci][2] = w4.z; wt[ci][3] = w4.w;
    }
    float cb[8];
    *(float4*)&cb[0] = *(const float4*)&conv_b[c8];
    *(float4*)&cb[4] = *(const float4*)&conv_b[c8 + 4];

#pragma unroll
    for (int rr = 0; rr < CROWS; ++rr) {
        const int row = r0 + rr;
        const int l = row & (L_SEQ - 1);
        float acc[8];
#pragma unroll
        for (int ci = 0; ci < 8; ++ci) acc[ci] = cb[ci];
#pragma unroll
        for (int h = 0; h < 4; ++h) {
            const int lsrc = l - 3 + h;
            if (lsrc >= 0) {
                float4 a = *(const float4*)&xz[(size_t)(row - 3 + h) * (2 * DINNER) + c8];
                float4 b = *(const float4*)&xz[(size_t)(row - 3 + h) * (2 * DINNER) + c8 + 4];
                acc[0] += a.x * wt[0][h]; acc[1] += a.y * wt[1][h];
                acc[2] += a.z * wt[2][h]; acc[3] += a.w * wt[3][h];
                acc[4] += b.x * wt[4][h]; acc[5] += b.y * wt[5][h];
                acc[6] += b.z * wt[6][h]; acc[7] += b.w * wt[7][h];
            }
        }
        float o[8];
        ushort8v ob;
#pragma unroll
        for (int ci = 0; ci < 8; ++ci) {
            o[ci] = acc[ci] / (1.f + __expf(-acc[ci]));
            sxc[rr][c8 + ci] = o[ci];
            ob[ci] = (short)f2bf(o[ci]);
        }
        *(float4*)&x_conv[(size_t)row * DINNER + c8]     = *(float4*)&o[0];
        *(float4*)&x_conv[(size_t)row * DINNER + c8 + 4] = *(float4*)&o[4];
        *(ushort8v*)&x_conv_bf[(size_t)row * DINNER + c8] = ob;
    }
    __syncthreads();

    // x_proj: g = channel group (256 ch), n = output index
    const int n = tid & 31;
    const int g = tid >> 5;
    float p[CROWS] = {};
    const int k0 = g * 256;
#pragma unroll 4
    for (int k = k0; k < k0 + 256; ++k) {
        const float wv = W_xp[k * 32 + n];
        p[0] += sxc[0][k] * wv;
        p[1] += sxc[1][k] * wv;
        p[2] += sxc[2][k] * wv;
        p[3] += sxc[3][k] * wv;
    }
#pragma unroll
    for (int rr = 0; rr < CROWS; ++rr) red[g][rr][n] = p[rr];
    __syncthreads();
    if (tid < CROWS * 32) {
        const int rr = tid >> 5;
        const int n2 = tid & 31;
        float s = b_xp[n2];
#pragma unroll
        for (int gg = 0; gg < 8; ++gg) s += red[gg][rr][n2];
        BC[(size_t)(r0 + rr) * 32 + n2] = s;
    }
}

// ---------------------------------------------------------------------------
// Chunked two-pass selective scan, states-in-registers.
// ---------------------------------------------------------------------------
__global__ __launch_bounds__(512) void scan_kernel(
    const float* __restrict__ delta, const float* __restrict__ x_conv,
    const float* __restrict__ BC, const float* __restrict__ A_log,
    const float* __restrict__ D_skip, const float* __restrict__ xz,
    unsigned short* __restrict__ y_bf)
{
    __shared__ float sA[DSTATE][CCH][DT];
    __shared__ float sH[DSTATE][CCH][DT];

    const int tid = threadIdx.x;
    const int dl  = tid & (DT - 1);
    const int c   = tid >> 4;
    const int b   = blockIdx.x >> 7;
    const int d0  = (blockIdx.x & 127) * DT;
    const int d   = d0 + dl;

    float Al[DSTATE];
#pragma unroll
    for (int s = 0; s < DSTATE; ++s)
        Al[s] = -__expf(A_log[d * DSTATE + s]) * 1.44269504f;
    const float Dsk = D_skip[d];

    float h[DSTATE];
#pragma unroll
    for (int s = 0; s < DSTATE; ++s) h[s] = 0.f;
    float dsum = 0.f;
    const int l0 = c * CS;

    for (int j = 0; j < CS; ++j) {
        const size_t r = (size_t)(b * L_SEQ + l0 + j);
        const float dt = delta[r * DINNER + d];
        const float xc = x_conv[r * DINNER + d];
        float Bv[DSTATE];
        *(float4*)&Bv[0]  = *(const float4*)&BC[r * 32 + 0];
        *(float4*)&Bv[4]  = *(const float4*)&BC[r * 32 + 4];
        *(float4*)&Bv[8]  = *(const float4*)&BC[r * 32 + 8];
        *(float4*)&Bv[12] = *(const float4*)&BC[r * 32 + 12];
        dsum += dt;
        const float dlx = dt * xc;
#pragma unroll
        for (int s = 0; s < DSTATE; ++s) {
            const float e = exp2f(dt * Al[s]);
            h[s] = e * h[s] + dlx * Bv[s];
        }
    }
#pragma unroll
    for (int s = 0; s < DSTATE; ++s) {
        sH[s][c][dl] = h[s];
        sA[s][c][dl] = exp2f(Al[s] * dsum);
    }
    __syncthreads();

    if (tid < DSTATE * DT) {
        const int dl2 = tid & (DT - 1);
        const int s2  = tid >> 4;
        float hh = 0.f;
#pragma unroll
        for (int c2 = 0; c2 < CCH; ++c2) {
            const float a  = sA[s2][c2][dl2];
            const float he = sH[s2][c2][dl2];
            sH[s2][c2][dl2] = hh;
            hh = a * hh + he;
        }
    }
    __syncthreads();

#pragma unroll
    for (int s = 0; s < DSTATE; ++s) h[s] = sH[s][c][dl];

    for (int j = 0; j < CS; ++j) {
        const size_t r = (size_t)(b * L_SEQ + l0 + j);
        const float dt = delta[r * DINNER + d];
        const float xc = x_conv[r * DINNER + d];
        const float z  = xz[r * (2 * DINNER) + DINNER + d];
        float Bv[DSTATE], Cv[DSTATE];
        *(float4*)&Bv[0]  = *(const float4*)&BC[r * 32 + 0];
        *(float4*)&Bv[4]  = *(const float4*)&BC[r * 32 + 4];
        *(float4*)&Bv[8]  = *(const float4*)&BC[r * 32 + 8];
        *(float4*)&Bv[12] = *(const float4*)&BC[r * 32 + 12];
        *(float4*)&Cv[0]  = *(const float4*)&BC[r * 32 + 16];
        *(float4*)&Cv[4]  = *(const float4*)&BC[r * 32 + 20];
        *(float4*)&Cv[8]  = *(const float4*)&BC[r * 32 + 24];
        *(float4*)&Cv[12] = *(const float4*)&BC[r * 32 + 28];
        const float dlx = dt * xc;
        float y = Dsk * xc;
#pragma unroll
        for (int s = 0; s < DSTATE; ++s) {
            const float e = exp2f(dt * Al[s]);
            h[s] = e * h[s] + dlx * Bv[s];
            y += h[s] * Cv[s];
        }
        const float g = z / (1.f + __expf(-z));
        y_bf[r * DINNER + d] = f2bf(y * g);
    }
}

// ---------------------------------------------------------------------------
// Row LayerNorm: unbiased variance (N-1), eps added to std.
// ---------------------------------------------------------------------------
__global__ __launch_bounds__(256) void layernorm_kernel(
    const float* __restrict__ t, const float* __restrict__ alpha,
    const float* __restrict__ beta, float* __restrict__ out)
{
    __shared__ float sred[4];
    __shared__ float sred2[4];
    const int row = blockIdx.x;
    const int tid = threadIdx.x;
    const float* r = t + (size_t)row * DMODEL;

    float4 v = *(const float4*)&r[tid * 4];
    float lsum = v.x + v.y + v.z + v.w;
#pragma unroll
    for (int m = 1; m < 64; m <<= 1) lsum += __shfl_xor(lsum, m);
    if ((tid & 63) == 0) sred[tid >> 6] = lsum;
    __syncthreads();
    const float mean = (sred[0] + sred[1] + sred[2] + sred[3]) * (1.f / DMODEL);

    const float dx = v.x - mean, dy = v.y - mean, dz = v.z - mean, dw = v.w - mean;
    float ls2 = dx * dx + dy * dy + dz * dz + dw * dw;
#pragma unroll
    for (int m = 1; m < 64; m <<= 1) ls2 += __shfl_xor(ls2, m);
    if ((tid & 63) == 0) sred2[tid >> 6] = ls2;
    __syncthreads();
    const float var = (sred2[0] + sred2[1] + sred2[2] + sred2[3]) * (1.f / (DMODEL - 1));
    const float inv = 1.f / (sqrtf(var) + EPSV);

    float4 a4 = *(const float4*)&alpha[tid * 4];
    float4 b4 = *(const float4*)&beta[tid * 4];
    float4 o;
    o.x = a4.x * dx * inv + b4.x;
    o.y = a4.y * dy * inv + b4.y;
    o.z = a4.z * dz * inv + b4.z;
    o.w = a4.w * dw * inv + b4.w;
    *(float4*)&out[(size_t)row * DMODEL + tid * 4] = o;
}

// ---------------------------------------------------------------------------
extern "C" void kernel_launch(void* const* d_in, const int* in_sizes, int n_in,
                              void* d_out, int out_size, void* d_ws, size_t ws_size,
                              hipStream_t stream)
{
    const float* x      = (const float*)d_in[0];
    const float* W_in   = (const float*)d_in[1];
    const float* b_in   = (const float*)d_in[2];
    const float* conv_w = (const float*)d_in[3];
    const float* conv_b = (const float*)d_in[4];
    const float* W_xp   = (const float*)d_in[5];
    const float* b_xp   = (const float*)d_in[6];
    const float* W_dt   = (const float*)d_in[7];
    const float* b_dt   = (const float*)d_in[8];
    const float* A_log  = (const float*)d_in[9];
    const float* D_skip = (const float*)d_in[10];
    const float* W_out  = (const float*)d_in[11];
    const float* b_out  = (const float*)d_in[12];
    const float* alpha  = (const float*)d_in[13];
    const float* beta   = (const float*)d_in[14];
    float* out = (float*)d_out;

    const size_t M = (size_t)B_SZ * L_SEQ;  // 2048 rows
    char* ws = (char*)d_ws;
    float* xz      = (float*)(ws + 0);                  // 32 MB (reused as tpre)
    float* x_conv  = (float*)(ws + (32u << 20));        // 16 MB
    float* delta   = (float*)(ws + (48u << 20));        // 16 MB
    float* BC      = (float*)(ws + (64u << 20));        // 0.5 MB
    unsigned short* x_bf       = (unsigned short*)(ws + (64u << 20) + (512u << 10)); // 4 MB
    unsigned short* W_in_t     = (unsigned short*)(ws + (69u << 20));  // 8 MB
    unsigned short* W_dt_t     = (unsigned short*)(ws + (77u << 20));  // 8 MB
    unsigned short* W_out_t    = (unsigned short*)(ws + (85u << 20));  // 4 MB
    unsigned short* x_conv_bf  = (unsigned short*)(ws + (89u << 20));  // 8 MB
    unsigned short* ygate_bf   = (unsigned short*)(ws + (77u << 20));  // reuse W_dt_t
    float* tpre = xz;

    const dim3 blk(256);

    cast_bf16_kernel<<<dim3((unsigned)(M * DMODEL / 4 / 256)), blk, 0, stream>>>(
        x, x_bf, (int)(M * DMODEL / 4));
    transpose_cast<<<dim3(2 * DINNER / 32, DMODEL / 32), blk, 0, stream>>>(
        W_in, W_in_t, DMODEL, 2 * DINNER);
    transpose_cast<<<dim3(DINNER / 32, DINNER / 32), blk, 0, stream>>>(
        W_dt, W_dt_t, DINNER, DINNER);
    transpose_cast<<<dim3(DMODEL / 32, DINNER / 32), blk, 0, stream>>>(
        W_out, W_out_t, DINNER, DMODEL);

    // 1. xz = x @ W_in + b_in        (2048 x 4096 x 1024)
    gemm_bf16<128, 128, 0><<<dim3(4096 / 128, 2048 / 128), blk, 0, stream>>>(
        x_bf, W_in_t, b_in, nullptr, xz, 2048, 4096, 1024);

    // 2+3. conv + SiLU + x_proj (fused)
    conv_xproj<<<dim3((unsigned)(M / CROWS)), blk, 0, stream>>>(
        xz, conv_w, conv_b, W_xp, b_xp, x_conv, x_conv_bf, BC);

    // 4. delta = softplus(x_conv @ W_dt + b_dt)   (2048 x 2048 x 2048)
    gemm_bf16<128, 128, 1><<<dim3(2048 / 128, 2048 / 128), blk, 0, stream>>>(
        x_conv_bf, W_dt_t, b_dt, nullptr, delta, 2048, 2048, 2048);

    // 5. chunked two-pass selective scan + D_skip + z-gate -> bf16
    scan_kernel<<<dim3(B_SZ * (DINNER / DT)), dim3(512), 0, stream>>>(
        delta, x_conv, BC, A_log, D_skip, xz, ygate_bf);

    // 6. tpre = ygate @ W_out + b_out + x   (2048 x 1024 x 2048), 128x64 tiles
    gemm_bf16<128, 64, 2><<<dim3(1024 / 64, 2048 / 128), blk, 0, stream>>>(
        ygate_bf, W_out_t, b_out, x, tpre, 2048, 1024, 2048);

    // 7. LayerNorm
    layernorm_kernel<<<dim3((unsigned)M), blk, 0, stream>>>(tpre, alpha, beta, out);
}

// Round 5
// 299.342 us; speedup vs baseline: 3.2417x; 1.0510x over previous
//
#include <hip/hip_runtime.h>
#include <math.h>

#define B_SZ    2
#define L_SEQ   1024
#define DMODEL  1024
#define DINNER  2048
#define DSTATE  16
#define EPSV    1e-6f

// scan decomposition
#define CCH 32
#define CS  (L_SEQ / CCH)
#define DT  16

typedef short  bf16x8  __attribute__((ext_vector_type(8)));
typedef float  floatx4 __attribute__((ext_vector_type(4)));
typedef unsigned short ushort8v __attribute__((ext_vector_type(8)));

__device__ __forceinline__ unsigned short f2bf(float f) {
    unsigned int u = __float_as_uint(f);
    unsigned int r = (u + 0x7FFFu + ((u >> 16) & 1u)) >> 16;
    return (unsigned short)r;
}

// ---------------------------------------------------------------------------
// fp32 -> bf16 elementwise cast
// ---------------------------------------------------------------------------
__global__ __launch_bounds__(256) void cast_bf16_kernel(
    const float* __restrict__ in, unsigned short* __restrict__ out, int n4)
{
    int i = blockIdx.x * 256 + threadIdx.x;
    if (i >= n4) return;
    float4 v = ((const float4*)in)[i];
    ushort4 o = { f2bf(v.x), f2bf(v.y), f2bf(v.z), f2bf(v.w) };
    ((ushort4*)out)[i] = o;
}

// ---------------------------------------------------------------------------
// W (KxN fp32) -> Wt (NxK bf16)
// ---------------------------------------------------------------------------
__global__ __launch_bounds__(256) void transpose_cast(
    const float* __restrict__ W, unsigned short* __restrict__ Wt, int K, int N)
{
    __shared__ float tile[32][33];
    const int n0 = blockIdx.x * 32;
    const int k0 = blockIdx.y * 32;
    const int c = threadIdx.x & 31;
    const int r = threadIdx.x >> 5;
#pragma unroll
    for (int i = 0; i < 4; ++i)
        tile[r + 8 * i][c] = W[(size_t)(k0 + r + 8 * i) * N + n0 + c];
    __syncthreads();
#pragma unroll
    for (int i = 0; i < 4; ++i)
        Wt[(size_t)(n0 + r + 8 * i) * K + k0 + c] = f2bf(tile[c][r + 8 * i]);
}

// ---------------------------------------------------------------------------
// bf16 MFMA GEMM — register-prefetch, single-buffered LDS, BK=64.
// TM x TN tile, 256 threads = 4 waves (2x2), wave tile (TM/2)x(TN/2),
// 16x16x32 MFMA. A: MxK, Bt: NxK (both bf16, K-contiguous).
// K-loop: load tile k+1 global->VGPR at top; compute tile k from LDS;
// barrier; ds_write prefetched regs (vmcnt drains HERE, after compute);
// barrier. XOR swizzle (16B chunk c of row r at position c^(r&7)) on both
// the ds_write and ds_read sides -> <=2-way (free).
// MODE 0: +bias; 1: softplus(+bias); 2: +bias + resid.
// ---------------------------------------------------------------------------
template <int TM, int TN, int MODE>
__global__ __launch_bounds__(256, 3) void gemm_bf16(
    const unsigned short* __restrict__ A, const unsigned short* __restrict__ Bt,
    const float* __restrict__ bias, const float* __restrict__ resid,
    float* __restrict__ C, int M, int N, int K)
{
    constexpr int MI = TM / 32;            // A 16-row tiles per wave
    constexpr int NJ = TN / 32;            // B 16-col tiles per wave
    constexpr int NLOAD = (TM + TN) / 32;  // 16B loads per thread per K-tile

    __shared__ unsigned short As[TM * 64];
    __shared__ unsigned short Bs[TN * 64];

    const int tid  = threadIdx.x;
    const int wave = tid >> 6;
    const int lane = tid & 63;
    const int m0 = blockIdx.y * TM;
    const int n0 = blockIdx.x * TN;
    const int wm = (wave >> 1) * (TM / 2);
    const int wn = (wave & 1) * (TN / 2);
    const int fr = lane & 15;
    const int kg = lane >> 4;              // k sub-chunk 0..3

    // staging map: slot = i*256+tid -> (row = slot>>3, chunk = slot&7)
    int offs[NLOAD];
    unsigned short* lp[NLOAD];
#pragma unroll
    for (int i = 0; i < NLOAD; ++i) {
        const int slot = i * 256 + tid;
        const int row  = slot >> 3;
        const int ch   = slot & 7;
        const int pos  = ch ^ (row & 7);
        if (i < TM / 32) {
            offs[i] = (m0 + row) * K + ch * 8;
            lp[i]   = &As[row * 64 + pos * 8];
        } else {
            const int rb = row - TM;
            offs[i] = (n0 + rb) * K + ch * 8;
            lp[i]   = &Bs[rb * 64 + pos * 8];
        }
    }

    floatx4 acc[MI][NJ] = {};
    bf16x8 pre[NLOAD];

    // prologue: tile 0
#pragma unroll
    for (int i = 0; i < NLOAD; ++i)
        pre[i] = *(const bf16x8*)((i < TM / 32 ? A : Bt) + offs[i]);
#pragma unroll
    for (int i = 0; i < NLOAD; ++i)
        *(bf16x8*)lp[i] = pre[i];
    __syncthreads();

    for (int kt = 0; kt < K; kt += 64) {
        const bool more = (kt + 64) < K;
        if (more) {
#pragma unroll
            for (int i = 0; i < NLOAD; ++i)
                pre[i] = *(const bf16x8*)((i < TM / 32 ? A : Bt) + offs[i] + kt + 64);
        }

#pragma unroll
        for (int ks = 0; ks < 2; ++ks) {
            const int cq = (ks << 2) | kg;
            bf16x8 af[MI], bfv[NJ];
#pragma unroll
            for (int i = 0; i < MI; ++i) {
                const int row = wm + i * 16 + fr;
                af[i] = *(const bf16x8*)&As[row * 64 + ((cq ^ (row & 7)) << 3)];
            }
#pragma unroll
            for (int j = 0; j < NJ; ++j) {
                const int row = wn + j * 16 + fr;
                bfv[j] = *(const bf16x8*)&Bs[row * 64 + ((cq ^ (row & 7)) << 3)];
            }
#pragma unroll
            for (int i = 0; i < MI; ++i)
#pragma unroll
                for (int j = 0; j < NJ; ++j)
                    acc[i][j] = __builtin_amdgcn_mfma_f32_16x16x32_bf16(
                        af[i], bfv[j], acc[i][j], 0, 0, 0);
        }
        __syncthreads();               // all waves done reading LDS
        if (more) {
#pragma unroll
            for (int i = 0; i < NLOAD; ++i)
                *(bf16x8*)lp[i] = pre[i];   // vmcnt wait lands here (post-compute)
        }
        __syncthreads();
    }

    // epilogue: C/D layout col=lane&15, row=(lane>>4)*4+reg
    const int rq = (lane >> 4) * 4;
#pragma unroll
    for (int i = 0; i < MI; ++i) {
#pragma unroll
        for (int j = 0; j < NJ; ++j) {
            const int col = n0 + wn + j * 16 + fr;
            const float bv = bias[col];
#pragma unroll
            for (int r = 0; r < 4; ++r) {
                const int row = m0 + wm + i * 16 + rq + r;
                float v = acc[i][j][r] + bv;
                if (MODE == 1) {
                    v = (v > 20.f) ? v : log1pf(__expf(v));
                } else if (MODE == 2) {
                    v += resid[(size_t)row * N + col];
                }
                C[(size_t)row * N + col] = v;
            }
        }
    }
}

// ---------------------------------------------------------------------------
// Fused depthwise causal conv1d(k=4) + SiLU + x_proj.
// ---------------------------------------------------------------------------
#define CROWS 4
__global__ __launch_bounds__(256) void conv_xproj(
    const float* __restrict__ xz, const float* __restrict__ conv_w,
    const float* __restrict__ conv_b, const float* __restrict__ W_xp,
    const float* __restrict__ b_xp, float* __restrict__ x_conv,
    unsigned short* __restrict__ x_conv_bf, float* __restrict__ BC)
{
    __shared__ float sxc[CROWS][DINNER];   // 32 KB
    __shared__ float red[8][CROWS][32];    // 4 KB

    const int tid = threadIdx.x;
    const int r0 = blockIdx.x * CROWS;
    const int c8 = tid * 8;

    float wt[8][4];
#pragma unroll
    for (int ci = 0; ci < 8; ++ci) {
        float4 w4 = *(const float4*)&conv_w[(c8 + ci) * 4];
        wt[ci][0] = w4.x; wt[ci][1] = w4.y; wt[ci][2] = w4.z; wt[ci][3] = w4.w;
    }
    float cb[8];
    *(float4*)&cb[0] = *(const float4*)&conv_b[c8];
    *(float4*)&cb[4] = *(const float4*)&conv_b[c8 + 4];

#pragma unroll
    for (int rr = 0; rr < CROWS; ++rr) {
        const int row = r0 + rr;
        const int l = row & (L_SEQ - 1);
        float acc[8];
#pragma unroll
        for (int ci = 0; ci < 8; ++ci) acc[ci] = cb[ci];
#pragma unroll
        for (int h = 0; h < 4; ++h) {
            const int lsrc = l - 3 + h;
            if (lsrc >= 0) {
                float4 a = *(const float4*)&xz[(size_t)(row - 3 + h) * (2 * DINNER) + c8];
                float4 b = *(const float4*)&xz[(size_t)(row - 3 + h) * (2 * DINNER) + c8 + 4];
                acc[0] += a.x * wt[0][h]; acc[1] += a.y * wt[1][h];
                acc[2] += a.z * wt[2][h]; acc[3] += a.w * wt[3][h];
                acc[4] += b.x * wt[4][h]; acc[5] += b.y * wt[5][h];
                acc[6] += b.z * wt[6][h]; acc[7] += b.w * wt[7][h];
            }
        }
        float o[8];
        ushort8v ob;
#pragma unroll
        for (int ci = 0; ci < 8; ++ci) {
            o[ci] = acc[ci] / (1.f + __expf(-acc[ci]));
            sxc[rr][c8 + ci] = o[ci];
            ob[ci] = (short)f2bf(o[ci]);
        }
        *(float4*)&x_conv[(size_t)row * DINNER + c8]     = *(float4*)&o[0];
        *(float4*)&x_conv[(size_t)row * DINNER + c8 + 4] = *(float4*)&o[4];
        *(ushort8v*)&x_conv_bf[(size_t)row * DINNER + c8] = ob;
    }
    __syncthreads();

    const int n = tid & 31;
    const int g = tid >> 5;
    float p[CROWS] = {};
    const int k0 = g * 256;
#pragma unroll 4
    for (int k = k0; k < k0 + 256; ++k) {
        const float wv = W_xp[k * 32 + n];
        p[0] += sxc[0][k] * wv;
        p[1] += sxc[1][k] * wv;
        p[2] += sxc[2][k] * wv;
        p[3] += sxc[3][k] * wv;
    }
#pragma unroll
    for (int rr = 0; rr < CROWS; ++rr) red[g][rr][n] = p[rr];
    __syncthreads();
    if (tid < CROWS * 32) {
        const int rr = tid >> 5;
        const int n2 = tid & 31;
        float s = b_xp[n2];
#pragma unroll
        for (int gg = 0; gg < 8; ++gg) s += red[gg][rr][n2];
        BC[(size_t)(r0 + rr) * 32 + n2] = s;
    }
}

// ---------------------------------------------------------------------------
// Chunked two-pass selective scan, states-in-registers.
// ---------------------------------------------------------------------------
__global__ __launch_bounds__(512) void scan_kernel(
    const float* __restrict__ delta, const float* __restrict__ x_conv,
    const float* __restrict__ BC, const float* __restrict__ A_log,
    const float* __restrict__ D_skip, const float* __restrict__ xz,
    unsigned short* __restrict__ y_bf)
{
    __shared__ float sA[DSTATE][CCH][DT];
    __shared__ float sH[DSTATE][CCH][DT];

    const int tid = threadIdx.x;
    const int dl  = tid & (DT - 1);
    const int c   = tid >> 4;
    const int b   = blockIdx.x >> 7;
    const int d0  = (blockIdx.x & 127) * DT;
    const int d   = d0 + dl;

    float Al[DSTATE];
#pragma unroll
    for (int s = 0; s < DSTATE; ++s)
        Al[s] = -__expf(A_log[d * DSTATE + s]) * 1.44269504f;
    const float Dsk = D_skip[d];

    float h[DSTATE];
#pragma unroll
    for (int s = 0; s < DSTATE; ++s) h[s] = 0.f;
    float dsum = 0.f;
    const int l0 = c * CS;

    for (int j = 0; j < CS; ++j) {
        const size_t r = (size_t)(b * L_SEQ + l0 + j);
        const float dt = delta[r * DINNER + d];
        const float xc = x_conv[r * DINNER + d];
        float Bv[DSTATE];
        *(float4*)&Bv[0]  = *(const float4*)&BC[r * 32 + 0];
        *(float4*)&Bv[4]  = *(const float4*)&BC[r * 32 + 4];
        *(float4*)&Bv[8]  = *(const float4*)&BC[r * 32 + 8];
        *(float4*)&Bv[12] = *(const float4*)&BC[r * 32 + 12];
        dsum += dt;
        const float dlx = dt * xc;
#pragma unroll
        for (int s = 0; s < DSTATE; ++s) {
            const float e = exp2f(dt * Al[s]);
            h[s] = e * h[s] + dlx * Bv[s];
        }
    }
#pragma unroll
    for (int s = 0; s < DSTATE; ++s) {
        sH[s][c][dl] = h[s];
        sA[s][c][dl] = exp2f(Al[s] * dsum);
    }
    __syncthreads();

    if (tid < DSTATE * DT) {
        const int dl2 = tid & (DT - 1);
        const int s2  = tid >> 4;
        float hh = 0.f;
#pragma unroll
        for (int c2 = 0; c2 < CCH; ++c2) {
            const float a  = sA[s2][c2][dl2];
            const float he = sH[s2][c2][dl2];
            sH[s2][c2][dl2] = hh;
            hh = a * hh + he;
        }
    }
    __syncthreads();

#pragma unroll
    for (int s = 0; s < DSTATE; ++s) h[s] = sH[s][c][dl];

    for (int j = 0; j < CS; ++j) {
        const size_t r = (size_t)(b * L_SEQ + l0 + j);
        const float dt = delta[r * DINNER + d];
        const float xc = x_conv[r * DINNER + d];
        const float z  = xz[r * (2 * DINNER) + DINNER + d];
        float Bv[DSTATE], Cv[DSTATE];
        *(float4*)&Bv[0]  = *(const float4*)&BC[r * 32 + 0];
        *(float4*)&Bv[4]  = *(const float4*)&BC[r * 32 + 4];
        *(float4*)&Bv[8]  = *(const float4*)&BC[r * 32 + 8];
        *(float4*)&Bv[12] = *(const float4*)&BC[r * 32 + 12];
        *(float4*)&Cv[0]  = *(const float4*)&BC[r * 32 + 16];
        *(float4*)&Cv[4]  = *(const float4*)&BC[r * 32 + 20];
        *(float4*)&Cv[8]  = *(const float4*)&BC[r * 32 + 24];
        *(float4*)&Cv[12] = *(const float4*)&BC[r * 32 + 28];
        const float dlx = dt * xc;
        float y = Dsk * xc;
#pragma unroll
        for (int s = 0; s < DSTATE; ++s) {
            const float e = exp2f(dt * Al[s]);
            h[s] = e * h[s] + dlx * Bv[s];
            y += h[s] * Cv[s];
        }
        const float g = z / (1.f + __expf(-z));
        y_bf[r * DINNER + d] = f2bf(y * g);
    }
}

// ---------------------------------------------------------------------------
// Row LayerNorm: unbiased variance (N-1), eps added to std.
// ---------------------------------------------------------------------------
__global__ __launch_bounds__(256) void layernorm_kernel(
    const float* __restrict__ t, const float* __restrict__ alpha,
    const float* __restrict__ beta, float* __restrict__ out)
{
    __shared__ float sred[4];
    __shared__ float sred2[4];
    const int row = blockIdx.x;
    const int tid = threadIdx.x;
    const float* r = t + (size_t)row * DMODEL;

    float4 v = *(const float4*)&r[tid * 4];
    float lsum = v.x + v.y + v.z + v.w;
#pragma unroll
    for (int m = 1; m < 64; m <<= 1) lsum += __shfl_xor(lsum, m);
    if ((tid & 63) == 0) sred[tid >> 6] = lsum;
    __syncthreads();
    const float mean = (sred[0] + sred[1] + sred[2] + sred[3]) * (1.f / DMODEL);

    const float dx = v.x - mean, dy = v.y - mean, dz = v.z - mean, dw = v.w - mean;
    float ls2 = dx * dx + dy * dy + dz * dz + dw * dw;
#pragma unroll
    for (int m = 1; m < 64; m <<= 1) ls2 += __shfl_xor(ls2, m);
    if ((tid & 63) == 0) sred2[tid >> 6] = ls2;
    __syncthreads();
    const float var = (sred2[0] + sred2[1] + sred2[2] + sred2[3]) * (1.f / (DMODEL - 1));
    const float inv = 1.f / (sqrtf(var) + EPSV);

    float4 a4 = *(const float4*)&alpha[tid * 4];
    float4 b4 = *(const float4*)&beta[tid * 4];
    float4 o;
    o.x = a4.x * dx * inv + b4.x;
    o.y = a4.y * dy * inv + b4.y;
    o.z = a4.z * dz * inv + b4.z;
    o.w = a4.w * dw * inv + b4.w;
    *(float4*)&out[(size_t)row * DMODEL + tid * 4] = o;
}

// ---------------------------------------------------------------------------
extern "C" void kernel_launch(void* const* d_in, const int* in_sizes, int n_in,
                              void* d_out, int out_size, void* d_ws, size_t ws_size,
                              hipStream_t stream)
{
    const float* x      = (const float*)d_in[0];
    const float* W_in   = (const float*)d_in[1];
    const float* b_in   = (const float*)d_in[2];
    const float* conv_w = (const float*)d_in[3];
    const float* conv_b = (const float*)d_in[4];
    const float* W_xp   = (const float*)d_in[5];
    const float* b_xp   = (const float*)d_in[6];
    const float* W_dt   = (const float*)d_in[7];
    const float* b_dt   = (const float*)d_in[8];
    const float* A_log  = (const float*)d_in[9];
    const float* D_skip = (const float*)d_in[10];
    const float* W_out  = (const float*)d_in[11];
    const float* b_out  = (const float*)d_in[12];
    const float* alpha  = (const float*)d_in[13];
    const float* beta   = (const float*)d_in[14];
    float* out = (float*)d_out;

    const size_t M = (size_t)B_SZ * L_SEQ;  // 2048 rows
    char* ws = (char*)d_ws;
    float* xz      = (float*)(ws + 0);                  // 32 MB (reused as tpre)
    float* x_conv  = (float*)(ws + (32u << 20));        // 16 MB
    float* delta   = (float*)(ws + (48u << 20));        // 16 MB
    float* BC      = (float*)(ws + (64u << 20));        // 0.5 MB
    unsigned short* x_bf       = (unsigned short*)(ws + (64u << 20) + (512u << 10)); // 4 MB
    unsigned short* W_in_t     = (unsigned short*)(ws + (69u << 20));  // 8 MB
    unsigned short* W_dt_t     = (unsigned short*)(ws + (77u << 20));  // 8 MB
    unsigned short* W_out_t    = (unsigned short*)(ws + (85u << 20));  // 4 MB
    unsigned short* x_conv_bf  = (unsigned short*)(ws + (89u << 20));  // 8 MB
    unsigned short* ygate_bf   = (unsigned short*)(ws + (77u << 20));  // reuse W_dt_t
    float* tpre = xz;

    const dim3 blk(256);

    cast_bf16_kernel<<<dim3((unsigned)(M * DMODEL / 4 / 256)), blk, 0, stream>>>(
        x, x_bf, (int)(M * DMODEL / 4));
    transpose_cast<<<dim3(2 * DINNER / 32, DMODEL / 32), blk, 0, stream>>>(
        W_in, W_in_t, DMODEL, 2 * DINNER);
    transpose_cast<<<dim3(DINNER / 32, DINNER / 32), blk, 0, stream>>>(
        W_dt, W_dt_t, DINNER, DINNER);
    transpose_cast<<<dim3(DMODEL / 32, DINNER / 32), blk, 0, stream>>>(
        W_out, W_out_t, DINNER, DMODEL);

    // 1. xz = x @ W_in + b_in        (2048 x 4096 x 1024), 1024 blocks = 4/CU
    gemm_bf16<128, 64, 0><<<dim3(4096 / 64, 2048 / 128), blk, 0, stream>>>(
        x_bf, W_in_t, b_in, nullptr, xz, 2048, 4096, 1024);

    // 2+3. conv + SiLU + x_proj (fused)
    conv_xproj<<<dim3((unsigned)(M / CROWS)), blk, 0, stream>>>(
        xz, conv_w, conv_b, W_xp, b_xp, x_conv, x_conv_bf, BC);

    // 4. delta = softplus(x_conv @ W_dt + b_dt)  (2048 x 2048 x 2048), 512 blocks
    gemm_bf16<128, 64, 1><<<dim3(2048 / 64, 2048 / 128), blk, 0, stream>>>(
        x_conv_bf, W_dt_t, b_dt, nullptr, delta, 2048, 2048, 2048);

    // 5. chunked two-pass selective scan + D_skip + z-gate -> bf16
    scan_kernel<<<dim3(B_SZ * (DINNER / DT)), dim3(512), 0, stream>>>(
        delta, x_conv, BC, A_log, D_skip, xz, ygate_bf);

    // 6. tpre = ygate @ W_out + b_out + x  (2048 x 1024 x 2048), 512 blocks
    gemm_bf16<64, 64, 2><<<dim3(1024 / 64, 2048 / 64), blk, 0, stream>>>(
        ygate_bf, W_out_t, b_out, x, tpre, 2048, 1024, 2048);

    // 7. LayerNorm
    layernorm_kernel<<<dim3((unsigned)M), blk, 0, stream>>>(tpre, alpha, beta, out);
}

// Round 6
// 295.352 us; speedup vs baseline: 3.2855x; 1.0135x over previous
//
#include <hip/hip_runtime.h>
#include <math.h>

#define B_SZ    2
#define L_SEQ   1024
#define DMODEL  1024
#define DINNER  2048
#define DSTATE  16
#define EPSV    1e-6f

// scan decomposition: 8 channels/block, 64 chunks of 16 steps
#define CCH 64
#define CS  (L_SEQ / CCH)      // 16
#define DT  8

typedef short  bf16x8  __attribute__((ext_vector_type(8)));
typedef float  floatx4 __attribute__((ext_vector_type(4)));
typedef unsigned short ushort8v __attribute__((ext_vector_type(8)));

__device__ __forceinline__ unsigned short f2bf(float f) {
    unsigned int u = __float_as_uint(f);
    unsigned int r = (u + 0x7FFFu + ((u >> 16) & 1u)) >> 16;
    return (unsigned short)r;
}

// ---------------------------------------------------------------------------
// fp32 -> bf16 elementwise cast
// ---------------------------------------------------------------------------
__global__ __launch_bounds__(256) void cast_bf16_kernel(
    const float* __restrict__ in, unsigned short* __restrict__ out, int n4)
{
    int i = blockIdx.x * 256 + threadIdx.x;
    if (i >= n4) return;
    float4 v = ((const float4*)in)[i];
    ushort4 o = { f2bf(v.x), f2bf(v.y), f2bf(v.z), f2bf(v.w) };
    ((ushort4*)out)[i] = o;
}

// ---------------------------------------------------------------------------
// W (KxN fp32) -> Wt (NxK bf16)
// ---------------------------------------------------------------------------
__global__ __launch_bounds__(256) void transpose_cast(
    const float* __restrict__ W, unsigned short* __restrict__ Wt, int K, int N)
{
    __shared__ float tile[32][33];
    const int n0 = blockIdx.x * 32;
    const int k0 = blockIdx.y * 32;
    const int c = threadIdx.x & 31;
    const int r = threadIdx.x >> 5;
#pragma unroll
    for (int i = 0; i < 4; ++i)
        tile[r + 8 * i][c] = W[(size_t)(k0 + r + 8 * i) * N + n0 + c];
    __syncthreads();
#pragma unroll
    for (int i = 0; i < 4; ++i)
        Wt[(size_t)(n0 + r + 8 * i) * K + k0 + c] = f2bf(tile[c][r + 8 * i]);
}

// ---------------------------------------------------------------------------
// bf16 MFMA GEMM — register-prefetch, single-buffered LDS, BK=64.
// (unchanged from round 5; XOR-swizzled, vmcnt drains post-compute)
// ---------------------------------------------------------------------------
template <int TM, int TN, int MODE>
__global__ __launch_bounds__(256, 3) void gemm_bf16(
    const unsigned short* __restrict__ A, const unsigned short* __restrict__ Bt,
    const float* __restrict__ bias, const float* __restrict__ resid,
    float* __restrict__ C, int M, int N, int K)
{
    constexpr int MI = TM / 32;
    constexpr int NJ = TN / 32;
    constexpr int NLOAD = (TM + TN) / 32;

    __shared__ unsigned short As[TM * 64];
    __shared__ unsigned short Bs[TN * 64];

    const int tid  = threadIdx.x;
    const int wave = tid >> 6;
    const int lane = tid & 63;
    const int m0 = blockIdx.y * TM;
    const int n0 = blockIdx.x * TN;
    const int wm = (wave >> 1) * (TM / 2);
    const int wn = (wave & 1) * (TN / 2);
    const int fr = lane & 15;
    const int kg = lane >> 4;

    int offs[NLOAD];
    unsigned short* lp[NLOAD];
#pragma unroll
    for (int i = 0; i < NLOAD; ++i) {
        const int slot = i * 256 + tid;
        const int row  = slot >> 3;
        const int ch   = slot & 7;
        const int pos  = ch ^ (row & 7);
        if (i < TM / 32) {
            offs[i] = (m0 + row) * K + ch * 8;
            lp[i]   = &As[row * 64 + pos * 8];
        } else {
            const int rb = row - TM;
            offs[i] = (n0 + rb) * K + ch * 8;
            lp[i]   = &Bs[rb * 64 + pos * 8];
        }
    }

    floatx4 acc[MI][NJ] = {};
    bf16x8 pre[NLOAD];

#pragma unroll
    for (int i = 0; i < NLOAD; ++i)
        pre[i] = *(const bf16x8*)((i < TM / 32 ? A : Bt) + offs[i]);
#pragma unroll
    for (int i = 0; i < NLOAD; ++i)
        *(bf16x8*)lp[i] = pre[i];
    __syncthreads();

    for (int kt = 0; kt < K; kt += 64) {
        const bool more = (kt + 64) < K;
        if (more) {
#pragma unroll
            for (int i = 0; i < NLOAD; ++i)
                pre[i] = *(const bf16x8*)((i < TM / 32 ? A : Bt) + offs[i] + kt + 64);
        }

#pragma unroll
        for (int ks = 0; ks < 2; ++ks) {
            const int cq = (ks << 2) | kg;
            bf16x8 af[MI], bfv[NJ];
#pragma unroll
            for (int i = 0; i < MI; ++i) {
                const int row = wm + i * 16 + fr;
                af[i] = *(const bf16x8*)&As[row * 64 + ((cq ^ (row & 7)) << 3)];
            }
#pragma unroll
            for (int j = 0; j < NJ; ++j) {
                const int row = wn + j * 16 + fr;
                bfv[j] = *(const bf16x8*)&Bs[row * 64 + ((cq ^ (row & 7)) << 3)];
            }
#pragma unroll
            for (int i = 0; i < MI; ++i)
#pragma unroll
                for (int j = 0; j < NJ; ++j)
                    acc[i][j] = __builtin_amdgcn_mfma_f32_16x16x32_bf16(
                        af[i], bfv[j], acc[i][j], 0, 0, 0);
        }
        __syncthreads();
        if (more) {
#pragma unroll
            for (int i = 0; i < NLOAD; ++i)
                *(bf16x8*)lp[i] = pre[i];
        }
        __syncthreads();
    }

    const int rq = (lane >> 4) * 4;
#pragma unroll
    for (int i = 0; i < MI; ++i) {
#pragma unroll
        for (int j = 0; j < NJ; ++j) {
            const int col = n0 + wn + j * 16 + fr;
            const float bv = bias[col];
#pragma unroll
            for (int r = 0; r < 4; ++r) {
                const int row = m0 + wm + i * 16 + rq + r;
                float v = acc[i][j][r] + bv;
                if (MODE == 1) {
                    v = (v > 20.f) ? v : log1pf(__expf(v));
                } else if (MODE == 2) {
                    v += resid[(size_t)row * N + col];
                }
                C[(size_t)row * N + col] = v;
            }
        }
    }
}

// ---------------------------------------------------------------------------
// Fused depthwise causal conv1d(k=4) + SiLU + x_proj.
// ---------------------------------------------------------------------------
#define CROWS 4
__global__ __launch_bounds__(256) void conv_xproj(
    const float* __restrict__ xz, const float* __restrict__ conv_w,
    const float* __restrict__ conv_b, const float* __restrict__ W_xp,
    const float* __restrict__ b_xp, float* __restrict__ x_conv,
    unsigned short* __restrict__ x_conv_bf, float* __restrict__ BC)
{
    __shared__ float sxc[CROWS][DINNER];   // 32 KB
    __shared__ float red[8][CROWS][32];    // 4 KB

    const int tid = threadIdx.x;
    const int r0 = blockIdx.x * CROWS;
    const int c8 = tid * 8;

    float wt[8][4];
#pragma unroll
    for (int ci = 0; ci < 8; ++ci) {
        float4 w4 = *(const float4*)&conv_w[(c8 + ci) * 4];
        wt[ci][0] = w4.x; wt[ci][1] = w4.y; wt[ci][2] = w4.z; wt[ci][3] = w4.w;
    }
    float cb[8];
    *(float4*)&cb[0] = *(const float4*)&conv_b[c8];
    *(float4*)&cb[4] = *(const float4*)&conv_b[c8 + 4];

#pragma unroll
    for (int rr = 0; rr < CROWS; ++rr) {
        const int row = r0 + rr;
        const int l = row & (L_SEQ - 1);
        float acc[8];
#pragma unroll
        for (int ci = 0; ci < 8; ++ci) acc[ci] = cb[ci];
#pragma unroll
        for (int h = 0; h < 4; ++h) {
            const int lsrc = l - 3 + h;
            if (lsrc >= 0) {
                float4 a = *(const float4*)&xz[(size_t)(row - 3 + h) * (2 * DINNER) + c8];
                float4 b = *(const float4*)&xz[(size_t)(row - 3 + h) * (2 * DINNER) + c8 + 4];
                acc[0] += a.x * wt[0][h]; acc[1] += a.y * wt[1][h];
                acc[2] += a.z * wt[2][h]; acc[3] += a.w * wt[3][h];
                acc[4] += b.x * wt[4][h]; acc[5] += b.y * wt[5][h];
                acc[6] += b.z * wt[6][h]; acc[7] += b.w * wt[7][h];
            }
        }
        float o[8];
        ushort8v ob;
#pragma unroll
        for (int ci = 0; ci < 8; ++ci) {
            o[ci] = acc[ci] / (1.f + __expf(-acc[ci]));
            sxc[rr][c8 + ci] = o[ci];
            ob[ci] = (short)f2bf(o[ci]);
        }
        *(float4*)&x_conv[(size_t)row * DINNER + c8]     = *(float4*)&o[0];
        *(float4*)&x_conv[(size_t)row * DINNER + c8 + 4] = *(float4*)&o[4];
        *(ushort8v*)&x_conv_bf[(size_t)row * DINNER + c8] = ob;
    }
    __syncthreads();

    const int n = tid & 31;
    const int g = tid >> 5;
    float p[CROWS] = {};
    const int k0 = g * 256;
#pragma unroll 4
    for (int k = k0; k < k0 + 256; ++k) {
        const float wv = W_xp[k * 32 + n];
        p[0] += sxc[0][k] * wv;
        p[1] += sxc[1][k] * wv;
        p[2] += sxc[2][k] * wv;
        p[3] += sxc[3][k] * wv;
    }
#pragma unroll
    for (int rr = 0; rr < CROWS; ++rr) red[g][rr][n] = p[rr];
    __syncthreads();
    if (tid < CROWS * 32) {
        const int rr = tid >> 5;
        const int n2 = tid & 31;
        float s = b_xp[n2];
#pragma unroll
        for (int gg = 0; gg < 8; ++gg) s += red[gg][rr][n2];
        BC[(size_t)(r0 + rr) * 32 + n2] = s;
    }
}

// ---------------------------------------------------------------------------
// Chunked two-pass selective scan, states-in-registers.
// Block: 512 threads = 8 channels x 64 chunks (CS=16). Grid: B * DINNER/8
// = 512 blocks -> 2 blocks/CU, 16 waves/CU (2x round-5 TLP, half the
// per-thread serial chain). LDS combine arrays use +1 s-stride pad to keep
// the combine phase's reads <=2-way.
// ---------------------------------------------------------------------------
#define SSTRIDE (CCH * DT + 1)
__global__ __launch_bounds__(512) void scan_kernel(
    const float* __restrict__ delta, const float* __restrict__ x_conv,
    const float* __restrict__ BC, const float* __restrict__ A_log,
    const float* __restrict__ D_skip, const float* __restrict__ xz,
    unsigned short* __restrict__ y_bf)
{
    __shared__ float sA[DSTATE * SSTRIDE];   // ~32.1 KB
    __shared__ float sH[DSTATE * SSTRIDE];   // ~32.1 KB

    const int tid = threadIdx.x;
    const int dl  = tid & (DT - 1);
    const int c   = tid >> 3;               // 0..63
    const int b   = blockIdx.x >> 8;
    const int d0  = (blockIdx.x & 255) * DT;
    const int d   = d0 + dl;

    float Al[DSTATE];
#pragma unroll
    for (int s = 0; s < DSTATE; ++s)
        Al[s] = -__expf(A_log[d * DSTATE + s]) * 1.44269504f;
    const float Dsk = D_skip[d];

    float h[DSTATE];
#pragma unroll
    for (int s = 0; s < DSTATE; ++s) h[s] = 0.f;
    float dsum = 0.f;
    const int l0 = c * CS;

    // ---- pass 1: chunk summaries from h=0 ----
#pragma unroll 2
    for (int j = 0; j < CS; ++j) {
        const size_t r = (size_t)(b * L_SEQ + l0 + j);
        const float dt = delta[r * DINNER + d];
        const float xc = x_conv[r * DINNER + d];
        float Bv[DSTATE];
        *(float4*)&Bv[0]  = *(const float4*)&BC[r * 32 + 0];
        *(float4*)&Bv[4]  = *(const float4*)&BC[r * 32 + 4];
        *(float4*)&Bv[8]  = *(const float4*)&BC[r * 32 + 8];
        *(float4*)&Bv[12] = *(const float4*)&BC[r * 32 + 12];
        dsum += dt;
        const float dlx = dt * xc;
#pragma unroll
        for (int s = 0; s < DSTATE; ++s) {
            const float e = exp2f(dt * Al[s]);
            h[s] = e * h[s] + dlx * Bv[s];
        }
    }
#pragma unroll
    for (int s = 0; s < DSTATE; ++s) {
        sH[s * SSTRIDE + c * DT + dl] = h[s];
        sA[s * SSTRIDE + c * DT + dl] = exp2f(Al[s] * dsum);
    }
    __syncthreads();

    // ---- combine: sequential over chunks, parallel over (s, dl) ----
    if (tid < DSTATE * DT) {
        const int dl2 = tid & (DT - 1);
        const int s2  = tid >> 3;
        float hh = 0.f;
#pragma unroll
        for (int c2 = 0; c2 < CCH; ++c2) {
            const int idx = s2 * SSTRIDE + c2 * DT + dl2;
            const float a  = sA[idx];
            const float he = sH[idx];
            sH[idx] = hh;
            hh = a * hh + he;
        }
    }
    __syncthreads();

#pragma unroll
    for (int s = 0; s < DSTATE; ++s) h[s] = sH[s * SSTRIDE + c * DT + dl];

    // ---- pass 2: rescan with true h0, fuse D_skip + silu(z) gate ----
#pragma unroll 2
    for (int j = 0; j < CS; ++j) {
        const size_t r = (size_t)(b * L_SEQ + l0 + j);
        const float dt = delta[r * DINNER + d];
        const float xc = x_conv[r * DINNER + d];
        const float z  = xz[r * (2 * DINNER) + DINNER + d];
        float Bv[DSTATE], Cv[DSTATE];
        *(float4*)&Bv[0]  = *(const float4*)&BC[r * 32 + 0];
        *(float4*)&Bv[4]  = *(const float4*)&BC[r * 32 + 4];
        *(float4*)&Bv[8]  = *(const float4*)&BC[r * 32 + 8];
        *(float4*)&Bv[12] = *(const float4*)&BC[r * 32 + 12];
        *(float4*)&Cv[0]  = *(const float4*)&BC[r * 32 + 16];
        *(float4*)&Cv[4]  = *(const float4*)&BC[r * 32 + 20];
        *(float4*)&Cv[8]  = *(const float4*)&BC[r * 32 + 24];
        *(float4*)&Cv[12] = *(const float4*)&BC[r * 32 + 28];
        const float dlx = dt * xc;
        float y = Dsk * xc;
#pragma unroll
        for (int s = 0; s < DSTATE; ++s) {
            const float e = exp2f(dt * Al[s]);
            h[s] = e * h[s] + dlx * Bv[s];
            y += h[s] * Cv[s];
        }
        const float g = z / (1.f + __expf(-z));
        y_bf[r * DINNER + d] = f2bf(y * g);
    }
}

// ---------------------------------------------------------------------------
// Row LayerNorm: unbiased variance (N-1), eps added to std.
// ---------------------------------------------------------------------------
__global__ __launch_bounds__(256) void layernorm_kernel(
    const float* __restrict__ t, const float* __restrict__ alpha,
    const float* __restrict__ beta, float* __restrict__ out)
{
    __shared__ float sred[4];
    __shared__ float sred2[4];
    const int row = blockIdx.x;
    const int tid = threadIdx.x;
    const float* r = t + (size_t)row * DMODEL;

    float4 v = *(const float4*)&r[tid * 4];
    float lsum = v.x + v.y + v.z + v.w;
#pragma unroll
    for (int m = 1; m < 64; m <<= 1) lsum += __shfl_xor(lsum, m);
    if ((tid & 63) == 0) sred[tid >> 6] = lsum;
    __syncthreads();
    const float mean = (sred[0] + sred[1] + sred[2] + sred[3]) * (1.f / DMODEL);

    const float dx = v.x - mean, dy = v.y - mean, dz = v.z - mean, dw = v.w - mean;
    float ls2 = dx * dx + dy * dy + dz * dz + dw * dw;
#pragma unroll
    for (int m = 1; m < 64; m <<= 1) ls2 += __shfl_xor(ls2, m);
    if ((tid & 63) == 0) sred2[tid >> 6] = ls2;
    __syncthreads();
    const float var = (sred2[0] + sred2[1] + sred2[2] + sred2[3]) * (1.f / (DMODEL - 1));
    const float inv = 1.f / (sqrtf(var) + EPSV);

    float4 a4 = *(const float4*)&alpha[tid * 4];
    float4 b4 = *(const float4*)&beta[tid * 4];
    float4 o;
    o.x = a4.x * dx * inv + b4.x;
    o.y = a4.y * dy * inv + b4.y;
    o.z = a4.z * dz * inv + b4.z;
    o.w = a4.w * dw * inv + b4.w;
    *(float4*)&out[(size_t)row * DMODEL + tid * 4] = o;
}

// ---------------------------------------------------------------------------
extern "C" void kernel_launch(void* const* d_in, const int* in_sizes, int n_in,
                              void* d_out, int out_size, void* d_ws, size_t ws_size,
                              hipStream_t stream)
{
    const float* x      = (const float*)d_in[0];
    const float* W_in   = (const float*)d_in[1];
    const float* b_in   = (const float*)d_in[2];
    const float* conv_w = (const float*)d_in[3];
    const float* conv_b = (const float*)d_in[4];
    const float* W_xp   = (const float*)d_in[5];
    const float* b_xp   = (const float*)d_in[6];
    const float* W_dt   = (const float*)d_in[7];
    const float* b_dt   = (const float*)d_in[8];
    const float* A_log  = (const float*)d_in[9];
    const float* D_skip = (const float*)d_in[10];
    const float* W_out  = (const float*)d_in[11];
    const float* b_out  = (const float*)d_in[12];
    const float* alpha  = (const float*)d_in[13];
    const float* beta   = (const float*)d_in[14];
    float* out = (float*)d_out;

    const size_t M = (size_t)B_SZ * L_SEQ;  // 2048 rows
    char* ws = (char*)d_ws;
    float* xz      = (float*)(ws + 0);                  // 32 MB (reused as tpre)
    float* x_conv  = (float*)(ws + (32u << 20));        // 16 MB
    float* delta   = (float*)(ws + (48u << 20));        // 16 MB
    float* BC      = (float*)(ws + (64u << 20));        // 0.5 MB
    unsigned short* x_bf       = (unsigned short*)(ws + (64u << 20) + (512u << 10)); // 4 MB
    unsigned short* W_in_t     = (unsigned short*)(ws + (69u << 20));  // 8 MB
    unsigned short* W_dt_t     = (unsigned short*)(ws + (77u << 20));  // 8 MB
    unsigned short* W_out_t    = (unsigned short*)(ws + (85u << 20));  // 4 MB
    unsigned short* x_conv_bf  = (unsigned short*)(ws + (89u << 20));  // 8 MB
    unsigned short* ygate_bf   = (unsigned short*)(ws + (77u << 20));  // reuse W_dt_t
    float* tpre = xz;

    const dim3 blk(256);

    cast_bf16_kernel<<<dim3((unsigned)(M * DMODEL / 4 / 256)), blk, 0, stream>>>(
        x, x_bf, (int)(M * DMODEL / 4));
    transpose_cast<<<dim3(2 * DINNER / 32, DMODEL / 32), blk, 0, stream>>>(
        W_in, W_in_t, DMODEL, 2 * DINNER);
    transpose_cast<<<dim3(DINNER / 32, DINNER / 32), blk, 0, stream>>>(
        W_dt, W_dt_t, DINNER, DINNER);
    transpose_cast<<<dim3(DMODEL / 32, DINNER / 32), blk, 0, stream>>>(
        W_out, W_out_t, DINNER, DMODEL);

    // 1. xz = x @ W_in + b_in        (2048 x 4096 x 1024), 1024 blocks
    gemm_bf16<128, 64, 0><<<dim3(4096 / 64, 2048 / 128), blk, 0, stream>>>(
        x_bf, W_in_t, b_in, nullptr, xz, 2048, 4096, 1024);

    // 2+3. conv + SiLU + x_proj (fused)
    conv_xproj<<<dim3((unsigned)(M / CROWS)), blk, 0, stream>>>(
        xz, conv_w, conv_b, W_xp, b_xp, x_conv, x_conv_bf, BC);

    // 4. delta = softplus(x_conv @ W_dt + b_dt)  (2048 x 2048 x 2048), 512 blocks
    gemm_bf16<128, 64, 1><<<dim3(2048 / 64, 2048 / 128), blk, 0, stream>>>(
        x_conv_bf, W_dt_t, b_dt, nullptr, delta, 2048, 2048, 2048);

    // 5. chunked two-pass selective scan + D_skip + z-gate -> bf16
    scan_kernel<<<dim3(B_SZ * (DINNER / DT)), dim3(512), 0, stream>>>(
        delta, x_conv, BC, A_log, D_skip, xz, ygate_bf);

    // 6. tpre = ygate @ W_out + b_out + x  (2048 x 1024 x 2048), 512 blocks
    gemm_bf16<64, 64, 2><<<dim3(1024 / 64, 2048 / 64), blk, 0, stream>>>(
        ygate_bf, W_out_t, b_out, x, tpre, 2048, 1024, 2048);

    // 7. LayerNorm
    layernorm_kernel<<<dim3((unsigned)M), blk, 0, stream>>>(tpre, alpha, beta, out);
}